// Round 1
// baseline (1394.388 us; speedup 1.0000x reference)
//
#include <hip/hip_runtime.h>

#define NN 100000
#define EE 1600000
#define GG 64
#define EPSF 1e-5f

// ---------------- CSR build ----------------

__global__ void count_edges(const int* __restrict__ dst, int* __restrict__ counts) {
  int e = blockIdx.x * blockDim.x + threadIdx.x;
  if (e < EE) atomicAdd(&counts[dst[e]], 1);
}

// single-block scan: rowptr[0]=0, rowptr[i+1] = inclusive_sum(counts[0..i])
__global__ void scan_counts(const int* __restrict__ counts, int* __restrict__ rowptr) {
  __shared__ int sdata[1024];
  __shared__ int s_carry;
  if (threadIdx.x == 0) { s_carry = 0; rowptr[0] = 0; }
  __syncthreads();
  for (int base = 0; base < NN; base += 1024) {
    int i = base + (int)threadIdx.x;
    int v = (i < NN) ? counts[i] : 0;
    sdata[threadIdx.x] = v;
    __syncthreads();
    for (int off = 1; off < 1024; off <<= 1) {
      int t = (threadIdx.x >= off) ? sdata[threadIdx.x - off] : 0;
      __syncthreads();
      sdata[threadIdx.x] += t;
      __syncthreads();
    }
    int incl = sdata[threadIdx.x] + s_carry;
    if (i < NN) rowptr[i + 1] = incl;
    __syncthreads();
    if (threadIdx.x == 1023) s_carry = incl;  // incl == old_carry + chunk_total
    __syncthreads();
  }
}

__global__ void prep_nodes(const int* __restrict__ counts, const int* __restrict__ rowptr,
                           float* __restrict__ dinv, int* __restrict__ cursor) {
  int i = blockIdx.x * blockDim.x + threadIdx.x;
  if (i < NN) {
    dinv[i] = rsqrtf((float)counts[i] + 1.0f);  // deg = in-degree + self-loop
    cursor[i] = rowptr[i];
  }
}

__global__ void fill_csr(const int* __restrict__ src, const int* __restrict__ dst,
                         int* __restrict__ cursor, int* __restrict__ csr_src) {
  int e = blockIdx.x * blockDim.x + threadIdx.x;
  if (e < EE) {
    int d = dst[e];
    int pos = atomicAdd(&cursor[d], 1);
    csr_src[pos] = src[e];
  }
}

// ---------------- GEMM: C[N,D] = A[N,K] @ W[K,D] ----------------
// block 256 threads, 32-row tile, K chunked by 32, 4x(D/32) micro-tile per thread.

template <int K, int D>
__global__ __launch_bounds__(256) void gemm_k(const float* __restrict__ A,
                                              const float* __restrict__ W,
                                              float* __restrict__ C) {
  constexpr int BM = 32, BK = 32;
  constexpr int NC = D / 32;  // 4 for D=128, 2 for D=64
  __shared__ float sA[BM][BK + 1];
  __shared__ float sW[BK][D];
  int tid = threadIdx.x;
  int row0 = blockIdx.x * BM;
  int tc = tid & 31;
  int tr = tid >> 5;  // 0..7
  float acc[4][NC];
#pragma unroll
  for (int i = 0; i < 4; ++i)
#pragma unroll
    for (int j = 0; j < NC; ++j) acc[i][j] = 0.f;

  for (int kk = 0; kk < K; kk += BK) {
    for (int i = tid; i < BM * BK; i += 256) {
      int r = i >> 5, c = i & 31;
      sA[r][c] = A[(size_t)(row0 + r) * K + kk + c];
    }
    for (int i = tid; i < BK * D; i += 256) {
      int r = i / D, c = i % D;
      sW[r][c] = W[(size_t)(kk + r) * D + c];
    }
    __syncthreads();
#pragma unroll
    for (int k = 0; k < BK; ++k) {
      float a[4];
#pragma unroll
      for (int i = 0; i < 4; ++i) a[i] = sA[tr + i * 8][k];
      float w[NC];
#pragma unroll
      for (int j = 0; j < NC; ++j) w[j] = sW[k][tc + j * 32];
#pragma unroll
      for (int i = 0; i < 4; ++i)
#pragma unroll
        for (int j = 0; j < NC; ++j) acc[i][j] += a[i] * w[j];
    }
    __syncthreads();
  }
#pragma unroll
  for (int i = 0; i < 4; ++i) {
    int gr = row0 + tr + i * 8;
#pragma unroll
    for (int j = 0; j < NC; ++j) C[(size_t)gr * D + tc + j * 32] = acc[i][j];
  }
}

// ---------------- Aggregation (atomic-free, CSR by dst) ----------------
// agg[n] = sum_{s in nbr(n)} xw[s]*dinv[s]*dinv[n] + xw[n]*dinv[n]^2 + bias
// optional fused BN(eval)+ReLU.

template <int D, bool BNRELU>
__global__ __launch_bounds__(256) void agg_k(
    const float* __restrict__ xw, const int* __restrict__ rowptr,
    const int* __restrict__ csr_src, const float* __restrict__ dinv,
    const float* __restrict__ bias, const float* __restrict__ bng,
    const float* __restrict__ bnb, const float* __restrict__ bnm,
    const float* __restrict__ bnv, float* __restrict__ out) {
  constexpr int NPB = 256 / D;
  int node = blockIdx.x * NPB + threadIdx.x / D;
  int c = threadIdx.x % D;
  if (node >= NN) return;
  float di = dinv[node];
  float acc = xw[(size_t)node * D + c] * (di * di);  // self-loop (norm = 1/deg)
  int beg = rowptr[node], end = rowptr[node + 1];
  for (int j = beg; j < end; ++j) {
    int s = csr_src[j];
    acc += xw[(size_t)s * D + c] * (dinv[s] * di);
  }
  acc += bias[c];
  if (BNRELU) {
    acc = (acc - bnm[c]) * rsqrtf(bnv[c] + EPSF) * bng[c] + bnb[c];
    acc = fmaxf(acc, 0.f);
  }
  out[(size_t)node * D + c] = acc;
}

// layer-2 aggregation fused with LayerNorm (D=64, one wave per node)
__global__ __launch_bounds__(256) void agg_ln_k(
    const float* __restrict__ xw, const int* __restrict__ rowptr,
    const int* __restrict__ csr_src, const float* __restrict__ dinv,
    const float* __restrict__ bias, const float* __restrict__ lng,
    const float* __restrict__ lnb, float* __restrict__ out) {
  int node = blockIdx.x * 4 + (threadIdx.x >> 6);
  int c = threadIdx.x & 63;
  if (node >= NN) return;
  float di = dinv[node];
  float acc = xw[(size_t)node * 64 + c] * (di * di);
  int beg = rowptr[node], end = rowptr[node + 1];
  for (int j = beg; j < end; ++j) {
    int s = csr_src[j];
    acc += xw[(size_t)s * 64 + c] * (dinv[s] * di);
  }
  acc += bias[c];
  float sum = acc;
#pragma unroll
  for (int off = 32; off > 0; off >>= 1) sum += __shfl_xor(sum, off, 64);
  float mu = sum * (1.f / 64.f);
  float d = acc - mu;
  float vs = d * d;
#pragma unroll
  for (int off = 32; off > 0; off >>= 1) vs += __shfl_xor(vs, off, 64);
  float var = vs * (1.f / 64.f);
  out[(size_t)node * 64 + c] = d * rsqrtf(var + EPSF) * lng[c] + lnb[c];
}

// ---------------- Pooling ----------------

__global__ void boundaries_k(const int* __restrict__ batch, int* __restrict__ start) {
  int i = blockIdx.x * blockDim.x + threadIdx.x;
  if (i >= NN) return;
  int b = batch[i];
  if (i == 0) {
    for (int g = 0; g <= b; ++g) start[g] = 0;
  } else {
    int p = batch[i - 1];
    for (int g = p + 1; g <= b; ++g) start[g] = i;
  }
  if (i == NN - 1) {
    for (int g = b + 1; g <= GG; ++g) start[g] = NN;
  }
}

__global__ __launch_bounds__(256) void pool_k(const float* __restrict__ ne,
                                              const int* __restrict__ start,
                                              float* __restrict__ ge) {
  __shared__ float red[256];
  int g = blockIdx.x;
  int tid = threadIdx.x;
  int c = tid & 63;
  int part = tid >> 6;  // 0..3
  int s = start[g], e = start[g + 1];
  float sum = 0.f;
  for (int i = s + part; i < e; i += 4) sum += ne[(size_t)i * 64 + c];
  red[tid] = sum;
  __syncthreads();
  if (part == 0) {
    float t = red[c] + red[c + 64] + red[c + 128] + red[c + 192];
    float cnt = (float)(e - s);
    ge[(size_t)g * 64 + c] = t / fmaxf(cnt, 1.f);
  }
}

// ---------------- launch ----------------

extern "C" void kernel_launch(void* const* d_in, const int* in_sizes, int n_in,
                              void* d_out, int out_size, void* d_ws, size_t ws_size,
                              hipStream_t stream) {
  const float* x = (const float*)d_in[0];
  const int* ei = (const int*)d_in[1];
  const int* srcv = ei;
  const int* dstv = ei + EE;
  const int* batch = (const int*)d_in[2];
  const float* W0 = (const float*)d_in[3];
  const float* b0 = (const float*)d_in[4];
  const float* W1 = (const float*)d_in[5];
  const float* b1 = (const float*)d_in[6];
  const float* W2 = (const float*)d_in[7];
  const float* b2 = (const float*)d_in[8];
  const float* bn0g = (const float*)d_in[9];
  const float* bn0b = (const float*)d_in[10];
  const float* bn0m = (const float*)d_in[11];
  const float* bn0v = (const float*)d_in[12];
  const float* bn1g = (const float*)d_in[13];
  const float* bn1b = (const float*)d_in[14];
  const float* bn1m = (const float*)d_in[15];
  const float* bn1v = (const float*)d_in[16];
  const float* lng = (const float*)d_in[17];
  const float* lnb = (const float*)d_in[18];

  float* out_nodes = (float*)d_out;
  float* out_graph = out_nodes + (size_t)NN * 64;

  // workspace carve-up (256B aligned)
  char* ws = (char*)d_ws;
  size_t off = 0;
  auto carve = [&](size_t bytes) {
    void* p = ws + off;
    off = (off + bytes + 255) & ~(size_t)255;
    return p;
  };
  int* counts = (int*)carve((size_t)NN * 4);
  int* rowptr = (int*)carve((size_t)(NN + 1) * 4);
  int* cursor = (int*)carve((size_t)NN * 4);
  int* csr_src = (int*)carve((size_t)EE * 4);
  float* dinv = (float*)carve((size_t)NN * 4);
  int* gstart = (int*)carve((size_t)(GG + 1) * 4);
  float* bufA = (float*)carve((size_t)NN * 128 * 4);
  float* bufB = (float*)carve((size_t)NN * 128 * 4);

  hipMemsetAsync(counts, 0, (size_t)NN * 4, stream);

  int eg = (EE + 255) / 256;   // 6250
  int ng = (NN + 255) / 256;   // 391

  count_edges<<<eg, 256, 0, stream>>>(dstv, counts);
  scan_counts<<<1, 1024, 0, stream>>>(counts, rowptr);
  prep_nodes<<<ng, 256, 0, stream>>>(counts, rowptr, dinv, cursor);
  fill_csr<<<eg, 256, 0, stream>>>(srcv, dstv, cursor, csr_src);
  boundaries_k<<<ng, 256, 0, stream>>>(batch, gstart);

  // layer 0: x[N,64] @ W0[64,128] -> bufA; agg+BN+ReLU -> bufB
  gemm_k<64, 128><<<NN / 32, 256, 0, stream>>>(x, W0, bufA);
  agg_k<128, true><<<NN / 2, 256, 0, stream>>>(bufA, rowptr, csr_src, dinv, b0,
                                               bn0g, bn0b, bn0m, bn0v, bufB);
  // layer 1: bufB @ W1[128,128] -> bufA; agg+BN+ReLU -> bufB
  gemm_k<128, 128><<<NN / 32, 256, 0, stream>>>(bufB, W1, bufA);
  agg_k<128, true><<<NN / 2, 256, 0, stream>>>(bufA, rowptr, csr_src, dinv, b1,
                                               bn1g, bn1b, bn1m, bn1v, bufB);
  // layer 2: bufB @ W2[128,64] -> bufA; agg + LayerNorm -> out_nodes
  gemm_k<128, 64><<<NN / 32, 256, 0, stream>>>(bufB, W2, bufA);
  agg_ln_k<<<NN / 4, 256, 0, stream>>>(bufA, rowptr, csr_src, dinv, b2, lng, lnb,
                                       out_nodes);
  // global mean pool
  pool_k<<<GG, 256, 0, stream>>>(out_nodes, gstart, out_graph);
}

// Round 2
// 926.042 us; speedup vs baseline: 1.5057x; 1.5057x over previous
//
#include <hip/hip_runtime.h>

#define NN 100000
#define EE 1600000
#define GG 64
#define EPSF 1e-5f
#define NB 391  // ceil(NN/256)

// ---------------- CSR build ----------------

__global__ void count_edges(const int* __restrict__ dst, int* __restrict__ counts) {
  int e = blockIdx.x * blockDim.x + threadIdx.x;
  if (e < EE) atomicAdd(&counts[dst[e]], 1);
}

// per-block inclusive scan + block totals
__global__ __launch_bounds__(256) void block_scan(const int* __restrict__ counts,
                                                  int* __restrict__ local_incl,
                                                  int* __restrict__ btot) {
  __shared__ int sd[256];
  int i = blockIdx.x * 256 + threadIdx.x;
  int v = (i < NN) ? counts[i] : 0;
  sd[threadIdx.x] = v;
  __syncthreads();
  for (int off = 1; off < 256; off <<= 1) {
    int t = (threadIdx.x >= off) ? sd[threadIdx.x - off] : 0;
    __syncthreads();
    sd[threadIdx.x] += t;
    __syncthreads();
  }
  if (i < NN) local_incl[i] = sd[threadIdx.x];
  if (threadIdx.x == 255) btot[blockIdx.x] = sd[255];
}

// single block scans the 391 block totals -> exclusive offsets
__global__ __launch_bounds__(512) void scan_totals(const int* __restrict__ btot,
                                                   int* __restrict__ boff) {
  __shared__ int sd[512];
  int v = (threadIdx.x < NB) ? btot[threadIdx.x] : 0;
  sd[threadIdx.x] = v;
  __syncthreads();
  for (int off = 1; off < 512; off <<= 1) {
    int t = (threadIdx.x >= off) ? sd[threadIdx.x - off] : 0;
    __syncthreads();
    sd[threadIdx.x] += t;
    __syncthreads();
  }
  boff[threadIdx.x] = sd[threadIdx.x] - v;  // exclusive
}

__global__ __launch_bounds__(256) void finalize_csr(const int* __restrict__ counts,
                                                    const int* __restrict__ local_incl,
                                                    const int* __restrict__ boff,
                                                    int* __restrict__ rowptr,
                                                    int* __restrict__ cursor,
                                                    float* __restrict__ dinv) {
  int i = blockIdx.x * 256 + threadIdx.x;
  if (i >= NN) return;
  int incl = local_incl[i] + boff[i >> 8];
  rowptr[i + 1] = incl;
  cursor[i] = incl - counts[i];
  dinv[i] = rsqrtf((float)counts[i] + 1.0f);
  if (i == 0) rowptr[0] = 0;
}

__global__ void fill_csr(const int* __restrict__ src, const int* __restrict__ dst,
                         int* __restrict__ cursor, int* __restrict__ csr_src) {
  int e = blockIdx.x * blockDim.x + threadIdx.x;
  if (e < EE) {
    int d = dst[e];
    int pos = atomicAdd(&cursor[d], 1);
    csr_src[pos] = src[e];
  }
}

// xs = x * dinv[row]  (row = 64 floats), float4-vectorized
__global__ __launch_bounds__(256) void premul_k(const float* __restrict__ x,
                                                const float* __restrict__ dinv,
                                                float* __restrict__ xs) {
  int i = blockIdx.x * 256 + threadIdx.x;  // float4 index
  if (i >= NN * 16) return;
  int n = i >> 4;
  float d = dinv[n];
  float4 v = ((const float4*)x)[i];
  v.x *= d; v.y *= d; v.z *= d; v.w *= d;
  ((float4*)xs)[i] = v;
}

// ---------------- Aggregation on premultiplied rows ----------------
// out[n] = dinv[n] * ( sum_{s in nbr(n)} xp[s] + xp[n] )

__global__ __launch_bounds__(256) void aggp64_k(const float* __restrict__ xp,
                                                const int* __restrict__ rowptr,
                                                const int* __restrict__ csr_src,
                                                const float* __restrict__ dinv,
                                                float* __restrict__ out) {
  int node = blockIdx.x * 4 + (threadIdx.x >> 6);
  int c = threadIdx.x & 63;
  if (node >= NN) return;
  float acc = xp[(size_t)node * 64 + c];
  int beg = rowptr[node], end = rowptr[node + 1];
  int j = beg;
  for (; j + 4 <= end; j += 4) {
    int s0 = csr_src[j], s1 = csr_src[j + 1], s2 = csr_src[j + 2], s3 = csr_src[j + 3];
    float v0 = xp[(size_t)s0 * 64 + c];
    float v1 = xp[(size_t)s1 * 64 + c];
    float v2 = xp[(size_t)s2 * 64 + c];
    float v3 = xp[(size_t)s3 * 64 + c];
    acc += (v0 + v1) + (v2 + v3);
  }
  for (; j < end; ++j) acc += xp[(size_t)csr_src[j] * 64 + c];
  out[(size_t)node * 64 + c] = acc * dinv[node];
}

__global__ __launch_bounds__(256) void aggp128_k(const float* __restrict__ xp,
                                                 const int* __restrict__ rowptr,
                                                 const int* __restrict__ csr_src,
                                                 const float* __restrict__ dinv,
                                                 float* __restrict__ out) {
  int node = blockIdx.x * 4 + (threadIdx.x >> 6);
  int c = threadIdx.x & 63;  // float2 lane
  if (node >= NN) return;
  const float2* xp2 = (const float2*)xp;
  float2 acc = xp2[(size_t)node * 64 + c];
  int beg = rowptr[node], end = rowptr[node + 1];
  int j = beg;
  for (; j + 4 <= end; j += 4) {
    int s0 = csr_src[j], s1 = csr_src[j + 1], s2 = csr_src[j + 2], s3 = csr_src[j + 3];
    float2 v0 = xp2[(size_t)s0 * 64 + c];
    float2 v1 = xp2[(size_t)s1 * 64 + c];
    float2 v2 = xp2[(size_t)s2 * 64 + c];
    float2 v3 = xp2[(size_t)s3 * 64 + c];
    acc.x += (v0.x + v1.x) + (v2.x + v3.x);
    acc.y += (v0.y + v1.y) + (v2.y + v3.y);
  }
  for (; j < end; ++j) {
    float2 v = xp2[(size_t)csr_src[j] * 64 + c];
    acc.x += v.x; acc.y += v.y;
  }
  float di = dinv[node];
  float2 o; o.x = acc.x * di; o.y = acc.y * di;
  ((float2*)out)[(size_t)node * 64 + c] = o;
}

// final agg + bias + LayerNorm (premultiplied 64-ch input)
__global__ __launch_bounds__(256) void agg_ln_k(const float* __restrict__ xp,
                                                const int* __restrict__ rowptr,
                                                const int* __restrict__ csr_src,
                                                const float* __restrict__ dinv,
                                                const float* __restrict__ bias,
                                                const float* __restrict__ lng,
                                                const float* __restrict__ lnb,
                                                float* __restrict__ out) {
  int node = blockIdx.x * 4 + (threadIdx.x >> 6);
  int c = threadIdx.x & 63;
  if (node >= NN) return;
  float acc = xp[(size_t)node * 64 + c];
  int beg = rowptr[node], end = rowptr[node + 1];
  int j = beg;
  for (; j + 4 <= end; j += 4) {
    int s0 = csr_src[j], s1 = csr_src[j + 1], s2 = csr_src[j + 2], s3 = csr_src[j + 3];
    float v0 = xp[(size_t)s0 * 64 + c];
    float v1 = xp[(size_t)s1 * 64 + c];
    float v2 = xp[(size_t)s2 * 64 + c];
    float v3 = xp[(size_t)s3 * 64 + c];
    acc += (v0 + v1) + (v2 + v3);
  }
  for (; j < end; ++j) acc += xp[(size_t)csr_src[j] * 64 + c];
  acc = acc * dinv[node] + bias[c];
  float sum = acc;
#pragma unroll
  for (int off = 32; off > 0; off >>= 1) sum += __shfl_xor(sum, off, 64);
  float mu = sum * (1.f / 64.f);
  float d = acc - mu;
  float vs = d * d;
#pragma unroll
  for (int off = 32; off > 0; off >>= 1) vs += __shfl_xor(vs, off, 64);
  float var = vs * (1.f / 64.f);
  out[(size_t)node * 64 + c] = d * rsqrtf(var + EPSF) * lng[c] + lnb[c];
}

// ---------------- GEMM: C[N,D] = A[N,K] @ W[K,D], fused epilogues ----------------
// 256 threads, BM=64 rows, BK=64, per-thread RPT rows x 4 cols.

#define EPI_BNRELU 1
#define EPI_BNRELU_PREMUL 2
#define EPI_PREMUL 3

template <int K, int D, int EPI>
__global__ __launch_bounds__(256) void gemm_k(
    const float* __restrict__ A, const float* __restrict__ W,
    const float* __restrict__ bias, const float* __restrict__ bng,
    const float* __restrict__ bnb, const float* __restrict__ bnm,
    const float* __restrict__ bnv, const float* __restrict__ dinv,
    float* __restrict__ C) {
  constexpr int BM = 64, BK = 64;
  constexpr int CG = D / 4;       // col groups: 32 (D=128) or 16 (D=64)
  constexpr int RG = 256 / CG;    // row groups: 8 or 16
  constexpr int RPT = BM / RG;    // rows per thread: 8 or 4
  __shared__ float sA[BM][BK + 4];
  __shared__ float sW[BK][D];
  int tid = threadIdx.x;
  int row0 = blockIdx.x * BM;
  int tc = tid % CG, trow = tid / CG;
  int c0 = tc * 4;
  float acc[RPT][4];
#pragma unroll
  for (int i = 0; i < RPT; ++i)
#pragma unroll
    for (int j = 0; j < 4; ++j) acc[i][j] = 0.f;

  for (int kk = 0; kk < K; kk += BK) {
    // stage A: BM x BK, float4 along K (coalesced)
#pragma unroll
    for (int t = 0; t < BM * BK / 1024; ++t) {
      int idx = tid + t * 256;
      int r = idx >> 4;        // BK/4 = 16 float4 per row
      int c4 = idx & 15;
      int gr = row0 + r;
      float4 v = make_float4(0.f, 0.f, 0.f, 0.f);
      if (gr < NN) v = *(const float4*)&A[(size_t)gr * K + kk + c4 * 4];
      *(float4*)&sA[r][c4 * 4] = v;
    }
    // stage W: BK x D
#pragma unroll
    for (int t = 0; t < BK * D / 1024; ++t) {
      int idx = tid + t * 256;
      int r = idx / CG;
      int c4 = idx % CG;
      *(float4*)&sW[r][c4 * 4] = *(const float4*)&W[(size_t)(kk + r) * D + c4 * 4];
    }
    __syncthreads();
#pragma unroll
    for (int k = 0; k < BK; ++k) {
      float4 w = *(const float4*)&sW[k][c0];
#pragma unroll
      for (int i = 0; i < RPT; ++i) {
        float a = sA[trow * RPT + i][k];
        acc[i][0] += a * w.x;
        acc[i][1] += a * w.y;
        acc[i][2] += a * w.z;
        acc[i][3] += a * w.w;
      }
    }
    __syncthreads();
  }

  // epilogue params for this thread's 4 columns
  float4 sc = make_float4(1.f, 1.f, 1.f, 1.f);
  float4 sh = make_float4(0.f, 0.f, 0.f, 0.f);
  if (EPI == EPI_BNRELU || EPI == EPI_BNRELU_PREMUL) {
    float4 g = *(const float4*)&bng[c0];
    float4 b = *(const float4*)&bnb[c0];
    float4 m = *(const float4*)&bnm[c0];
    float4 v = *(const float4*)&bnv[c0];
    float4 bi = *(const float4*)&bias[c0];
    sc.x = g.x * rsqrtf(v.x + EPSF); sc.y = g.y * rsqrtf(v.y + EPSF);
    sc.z = g.z * rsqrtf(v.z + EPSF); sc.w = g.w * rsqrtf(v.w + EPSF);
    sh.x = b.x + (bi.x - m.x) * sc.x; sh.y = b.y + (bi.y - m.y) * sc.y;
    sh.z = b.z + (bi.z - m.z) * sc.z; sh.w = b.w + (bi.w - m.w) * sc.w;
  }
#pragma unroll
  for (int i = 0; i < RPT; ++i) {
    int gr = row0 + trow * RPT + i;
    if (gr >= NN) continue;
    float4 o;
    o.x = acc[i][0]; o.y = acc[i][1]; o.z = acc[i][2]; o.w = acc[i][3];
    if (EPI == EPI_BNRELU || EPI == EPI_BNRELU_PREMUL) {
      o.x = fmaxf(o.x * sc.x + sh.x, 0.f);
      o.y = fmaxf(o.y * sc.y + sh.y, 0.f);
      o.z = fmaxf(o.z * sc.z + sh.z, 0.f);
      o.w = fmaxf(o.w * sc.w + sh.w, 0.f);
    }
    if (EPI == EPI_BNRELU_PREMUL || EPI == EPI_PREMUL) {
      float d = dinv[gr];
      o.x *= d; o.y *= d; o.z *= d; o.w *= d;
    }
    *(float4*)&C[(size_t)gr * D + c0] = o;
  }
}

// ---------------- Pooling ----------------

__global__ void boundaries_k(const int* __restrict__ batch, int* __restrict__ start) {
  int i = blockIdx.x * blockDim.x + threadIdx.x;
  if (i >= NN) return;
  int b = batch[i];
  if (i == 0) {
    for (int g = 0; g <= b; ++g) start[g] = 0;
  } else {
    int p = batch[i - 1];
    for (int g = p + 1; g <= b; ++g) start[g] = i;
  }
  if (i == NN - 1) {
    for (int g = b + 1; g <= GG; ++g) start[g] = NN;
  }
}

__global__ __launch_bounds__(256) void pool_k(const float* __restrict__ ne,
                                              const int* __restrict__ start,
                                              float* __restrict__ ge) {
  __shared__ float red[256];
  int g = blockIdx.x;
  int tid = threadIdx.x;
  int c = tid & 63;
  int part = tid >> 6;
  int s = start[g], e = start[g + 1];
  float sum = 0.f;
  for (int i = s + part; i < e; i += 4) sum += ne[(size_t)i * 64 + c];
  red[tid] = sum;
  __syncthreads();
  if (part == 0) {
    float t = red[c] + red[c + 64] + red[c + 128] + red[c + 192];
    float cnt = (float)(e - s);
    ge[(size_t)g * 64 + c] = t / fmaxf(cnt, 1.f);
  }
}

// ---------------- launch ----------------

extern "C" void kernel_launch(void* const* d_in, const int* in_sizes, int n_in,
                              void* d_out, int out_size, void* d_ws, size_t ws_size,
                              hipStream_t stream) {
  const float* x = (const float*)d_in[0];
  const int* ei = (const int*)d_in[1];
  const int* srcv = ei;
  const int* dstv = ei + EE;
  const int* batch = (const int*)d_in[2];
  const float* W0 = (const float*)d_in[3];
  const float* b0 = (const float*)d_in[4];
  const float* W1 = (const float*)d_in[5];
  const float* b1 = (const float*)d_in[6];
  const float* W2 = (const float*)d_in[7];
  const float* b2 = (const float*)d_in[8];
  const float* bn0g = (const float*)d_in[9];
  const float* bn0b = (const float*)d_in[10];
  const float* bn0m = (const float*)d_in[11];
  const float* bn0v = (const float*)d_in[12];
  const float* bn1g = (const float*)d_in[13];
  const float* bn1b = (const float*)d_in[14];
  const float* bn1m = (const float*)d_in[15];
  const float* bn1v = (const float*)d_in[16];
  const float* lng = (const float*)d_in[17];
  const float* lnb = (const float*)d_in[18];

  float* out_nodes = (float*)d_out;
  float* out_graph = out_nodes + (size_t)NN * 64;

  char* ws = (char*)d_ws;
  size_t off = 0;
  auto carve = [&](size_t bytes) {
    void* p = ws + off;
    off = (off + bytes + 255) & ~(size_t)255;
    return p;
  };
  int* counts = (int*)carve((size_t)NN * 4);
  int* local_incl = (int*)carve((size_t)NN * 4);
  int* btot = (int*)carve(512 * 4);
  int* boff = (int*)carve(512 * 4);
  int* rowptr = (int*)carve((size_t)(NN + 1) * 4);
  int* cursor = (int*)carve((size_t)NN * 4);
  int* csr_src = (int*)carve((size_t)EE * 4);
  float* dinv = (float*)carve((size_t)NN * 4);
  int* gstart = (int*)carve((size_t)(GG + 1) * 4);
  float* bufA = (float*)carve((size_t)NN * 128 * 4);
  float* bufB = (float*)carve((size_t)NN * 128 * 4);

  hipMemsetAsync(counts, 0, (size_t)NN * 4, stream);

  int eg = (EE + 255) / 256;  // 6250
  int ng = NB;                // 391

  count_edges<<<eg, 256, 0, stream>>>(dstv, counts);
  block_scan<<<ng, 256, 0, stream>>>(counts, local_incl, btot);
  scan_totals<<<1, 512, 0, stream>>>(btot, boff);
  finalize_csr<<<ng, 256, 0, stream>>>(counts, local_incl, boff, rowptr, cursor, dinv);
  fill_csr<<<eg, 256, 0, stream>>>(srcv, dstv, cursor, csr_src);
  boundaries_k<<<ng, 256, 0, stream>>>(batch, gstart);

  int agrid = (NN + 3) / 4;      // 25000
  int ggrid = (NN + 63) / 64;    // 1563

  // xs = x * dinv  -> bufA[:, :64]
  premul_k<<<(NN * 16 + 255) / 256, 256, 0, stream>>>(x, dinv, bufA);
  // a0 = agg(xs) -> bufB   (64 ch)
  aggp64_k<<<agrid, 256, 0, stream>>>(bufA, rowptr, csr_src, dinv, bufB);
  // h0p = relu(BN(a0@W0 + b0)) * dinv -> bufA  (128 ch)
  gemm_k<64, 128, EPI_BNRELU_PREMUL><<<ggrid, 256, 0, stream>>>(
      bufB, W0, b0, bn0g, bn0b, bn0m, bn0v, dinv, bufA);
  // a1 = agg(h0p) -> bufB  (128 ch)
  aggp128_k<<<agrid, 256, 0, stream>>>(bufA, rowptr, csr_src, dinv, bufB);
  // h1 = relu(BN(a1@W1 + b1)) -> bufA  (128 ch, NOT premultiplied)
  gemm_k<128, 128, EPI_BNRELU><<<ggrid, 256, 0, stream>>>(
      bufB, W1, b1, bn1g, bn1b, bn1m, bn1v, dinv, bufA);
  // xw2p = (h1@W2) * dinv -> bufB  (64 ch; bias b2 applied post-agg)
  gemm_k<128, 64, EPI_PREMUL><<<ggrid, 256, 0, stream>>>(
      bufA, W2, b2, bn1g, bn1b, bn1m, bn1v, dinv, bufB);
  // out_nodes = LN(agg(xw2p) + b2)
  agg_ln_k<<<agrid, 256, 0, stream>>>(bufB, rowptr, csr_src, dinv, b2, lng, lnb,
                                      out_nodes);
  // graph mean pool
  pool_k<<<GG, 256, 0, stream>>>(out_nodes, gstart, out_graph);
}

// Round 3
// 680.224 us; speedup vs baseline: 2.0499x; 1.3614x over previous
//
#include <hip/hip_runtime.h>

#define NN 100000
#define EE 1600000
#define GG 64
#define EPSF 1e-5f
#define NB 391  // ceil(NN/256)

// ---------------- CSR build ----------------

__global__ void count_edges(const int* __restrict__ dst, int* __restrict__ counts) {
  int e = blockIdx.x * blockDim.x + threadIdx.x;
  if (e < EE) atomicAdd(&counts[dst[e]], 1);
}

// per-block inclusive scan + block totals
__global__ __launch_bounds__(256) void block_scan(const int* __restrict__ counts,
                                                  int* __restrict__ local_incl,
                                                  int* __restrict__ btot) {
  __shared__ int sd[256];
  int i = blockIdx.x * 256 + threadIdx.x;
  int v = (i < NN) ? counts[i] : 0;
  sd[threadIdx.x] = v;
  __syncthreads();
  for (int off = 1; off < 256; off <<= 1) {
    int t = (threadIdx.x >= off) ? sd[threadIdx.x - off] : 0;
    __syncthreads();
    sd[threadIdx.x] += t;
    __syncthreads();
  }
  if (i < NN) local_incl[i] = sd[threadIdx.x];
  if (threadIdx.x == 255) btot[blockIdx.x] = sd[255];
}

// single block scans the 391 block totals -> exclusive offsets
__global__ __launch_bounds__(512) void scan_totals(const int* __restrict__ btot,
                                                   int* __restrict__ boff) {
  __shared__ int sd[512];
  int v = (threadIdx.x < NB) ? btot[threadIdx.x] : 0;
  sd[threadIdx.x] = v;
  __syncthreads();
  for (int off = 1; off < 512; off <<= 1) {
    int t = (threadIdx.x >= off) ? sd[threadIdx.x - off] : 0;
    __syncthreads();
    sd[threadIdx.x] += t;
    __syncthreads();
  }
  boff[threadIdx.x] = sd[threadIdx.x] - v;  // exclusive
}

__global__ __launch_bounds__(256) void finalize_csr(const int* __restrict__ counts,
                                                    const int* __restrict__ local_incl,
                                                    const int* __restrict__ boff,
                                                    int* __restrict__ rowptr,
                                                    int* __restrict__ cursor,
                                                    float* __restrict__ dinv) {
  int i = blockIdx.x * 256 + threadIdx.x;
  if (i >= NN) return;
  int incl = local_incl[i] + boff[i >> 8];
  rowptr[i + 1] = incl;
  cursor[i] = incl - counts[i];
  dinv[i] = rsqrtf((float)counts[i] + 1.0f);
  if (i == 0) rowptr[0] = 0;
}

__global__ void fill_csr(const int* __restrict__ src, const int* __restrict__ dst,
                         int* __restrict__ cursor, int* __restrict__ csr_src) {
  int e = blockIdx.x * blockDim.x + threadIdx.x;
  if (e < EE) {
    int d = dst[e];
    int pos = atomicAdd(&cursor[d], 1);
    csr_src[pos] = src[e];
  }
}

// xs = x * dinv[row]  (row = 64 floats), float4-vectorized
__global__ __launch_bounds__(256) void premul_k(const float* __restrict__ x,
                                                const float* __restrict__ dinv,
                                                float* __restrict__ xs) {
  int i = blockIdx.x * 256 + threadIdx.x;  // float4 index
  if (i >= NN * 16) return;
  int n = i >> 4;
  float d = dinv[n];
  float4 v = ((const float4*)x)[i];
  v.x *= d; v.y *= d; v.z *= d; v.w *= d;
  ((float4*)xs)[i] = v;
}

// ---------------- Aggregation on premultiplied rows ----------------
// out[n] = dinv[n] * ( sum_{s in nbr(n)} xp[s] + xp[n] )

__global__ __launch_bounds__(256) void aggp64_k(const float* __restrict__ xp,
                                                const int* __restrict__ rowptr,
                                                const int* __restrict__ csr_src,
                                                const float* __restrict__ dinv,
                                                float* __restrict__ out) {
  int node = blockIdx.x * 4 + (threadIdx.x >> 6);
  int c = threadIdx.x & 63;
  if (node >= NN) return;
  float acc = xp[(size_t)node * 64 + c];
  int beg = rowptr[node], end = rowptr[node + 1];
  int j = beg;
  for (; j + 4 <= end; j += 4) {
    int s0 = csr_src[j], s1 = csr_src[j + 1], s2 = csr_src[j + 2], s3 = csr_src[j + 3];
    float v0 = xp[(size_t)s0 * 64 + c];
    float v1 = xp[(size_t)s1 * 64 + c];
    float v2 = xp[(size_t)s2 * 64 + c];
    float v3 = xp[(size_t)s3 * 64 + c];
    acc += (v0 + v1) + (v2 + v3);
  }
  for (; j < end; ++j) acc += xp[(size_t)csr_src[j] * 64 + c];
  out[(size_t)node * 64 + c] = acc * dinv[node];
}

__global__ __launch_bounds__(256) void aggp128_k(const float* __restrict__ xp,
                                                 const int* __restrict__ rowptr,
                                                 const int* __restrict__ csr_src,
                                                 const float* __restrict__ dinv,
                                                 float* __restrict__ out) {
  int node = blockIdx.x * 4 + (threadIdx.x >> 6);
  int c = threadIdx.x & 63;  // float2 lane
  if (node >= NN) return;
  const float2* xp2 = (const float2*)xp;
  float2 acc = xp2[(size_t)node * 64 + c];
  int beg = rowptr[node], end = rowptr[node + 1];
  int j = beg;
  for (; j + 4 <= end; j += 4) {
    int s0 = csr_src[j], s1 = csr_src[j + 1], s2 = csr_src[j + 2], s3 = csr_src[j + 3];
    float2 v0 = xp2[(size_t)s0 * 64 + c];
    float2 v1 = xp2[(size_t)s1 * 64 + c];
    float2 v2 = xp2[(size_t)s2 * 64 + c];
    float2 v3 = xp2[(size_t)s3 * 64 + c];
    acc.x += (v0.x + v1.x) + (v2.x + v3.x);
    acc.y += (v0.y + v1.y) + (v2.y + v3.y);
  }
  for (; j < end; ++j) {
    float2 v = xp2[(size_t)csr_src[j] * 64 + c];
    acc.x += v.x; acc.y += v.y;
  }
  float di = dinv[node];
  float2 o; o.x = acc.x * di; o.y = acc.y * di;
  ((float2*)out)[(size_t)node * 64 + c] = o;
}

// final agg + bias + LayerNorm (premultiplied 64-ch input)
__global__ __launch_bounds__(256) void agg_ln_k(const float* __restrict__ xp,
                                                const int* __restrict__ rowptr,
                                                const int* __restrict__ csr_src,
                                                const float* __restrict__ dinv,
                                                const float* __restrict__ bias,
                                                const float* __restrict__ lng,
                                                const float* __restrict__ lnb,
                                                float* __restrict__ out) {
  int node = blockIdx.x * 4 + (threadIdx.x >> 6);
  int c = threadIdx.x & 63;
  if (node >= NN) return;
  float acc = xp[(size_t)node * 64 + c];
  int beg = rowptr[node], end = rowptr[node + 1];
  int j = beg;
  for (; j + 4 <= end; j += 4) {
    int s0 = csr_src[j], s1 = csr_src[j + 1], s2 = csr_src[j + 2], s3 = csr_src[j + 3];
    float v0 = xp[(size_t)s0 * 64 + c];
    float v1 = xp[(size_t)s1 * 64 + c];
    float v2 = xp[(size_t)s2 * 64 + c];
    float v3 = xp[(size_t)s3 * 64 + c];
    acc += (v0 + v1) + (v2 + v3);
  }
  for (; j < end; ++j) acc += xp[(size_t)csr_src[j] * 64 + c];
  acc = acc * dinv[node] + bias[c];
  float sum = acc;
#pragma unroll
  for (int off = 32; off > 0; off >>= 1) sum += __shfl_xor(sum, off, 64);
  float mu = sum * (1.f / 64.f);
  float d = acc - mu;
  float vs = d * d;
#pragma unroll
  for (int off = 32; off > 0; off >>= 1) vs += __shfl_xor(vs, off, 64);
  float var = vs * (1.f / 64.f);
  out[(size_t)node * 64 + c] = d * rsqrtf(var + EPSF) * lng[c] + lnb[c];
}

// ---------------- GEMM: C[N,D] = A[N,K] @ W[K,D], fused epilogues ----------------
// 256 threads, BM=64 rows, BK=32; VGPR-capped (launch_bounds min 2 waves/EU),
// k-loop unroll limited to 4 to stop the scheduler hoisting the whole tile.

#define EPI_BNRELU 1
#define EPI_BNRELU_PREMUL 2
#define EPI_PREMUL 3

template <int K, int D, int EPI>
__global__ __launch_bounds__(256, 2) void gemm_k(
    const float* __restrict__ A, const float* __restrict__ W,
    const float* __restrict__ bias, const float* __restrict__ bng,
    const float* __restrict__ bnb, const float* __restrict__ bnm,
    const float* __restrict__ bnv, const float* __restrict__ dinv,
    float* __restrict__ C) {
  constexpr int BM = 64, BK = 32;
  constexpr int CG = D / 4;       // col groups: 32 (D=128) or 16 (D=64)
  constexpr int RG = 256 / CG;    // row groups: 8 or 16
  constexpr int RPT = BM / RG;    // rows per thread: 8 or 4
  __shared__ float sA[BM][BK + 4];   // stride 36 floats: float4-aligned
  __shared__ float sW[BK][D];
  int tid = threadIdx.x;
  int row0 = blockIdx.x * BM;
  int tc = tid % CG, trow = tid / CG;
  int c0 = tc * 4;
  float acc[RPT][4];
#pragma unroll
  for (int i = 0; i < RPT; ++i)
#pragma unroll
    for (int j = 0; j < 4; ++j) acc[i][j] = 0.f;

  for (int kk = 0; kk < K; kk += BK) {
    // stage A: BM x BK, float4 along K (coalesced). BM*BK/4/256 = 2 per thread.
#pragma unroll
    for (int t = 0; t < BM * BK / 1024; ++t) {
      int idx = tid + t * 256;
      int r = idx >> 3;        // BK/4 = 8 float4 per row
      int c4 = idx & 7;
      int gr = row0 + r;
      float4 v = make_float4(0.f, 0.f, 0.f, 0.f);
      if (gr < NN) v = *(const float4*)&A[(size_t)gr * K + kk + c4 * 4];
      *(float4*)&sA[r][c4 * 4] = v;
    }
    // stage W: BK x D
#pragma unroll
    for (int t = 0; t < BK * D / 1024; ++t) {
      int idx = tid + t * 256;
      int r = idx / CG;
      int c4 = idx % CG;
      *(float4*)&sW[r][c4 * 4] = *(const float4*)&W[(size_t)(kk + r) * D + c4 * 4];
    }
    __syncthreads();
#pragma unroll 4
    for (int k = 0; k < BK; ++k) {
      float4 w = *(const float4*)&sW[k][c0];
#pragma unroll
      for (int i = 0; i < RPT; ++i) {
        float a = sA[trow * RPT + i][k];
        acc[i][0] += a * w.x;
        acc[i][1] += a * w.y;
        acc[i][2] += a * w.z;
        acc[i][3] += a * w.w;
      }
    }
    __syncthreads();
  }

  // epilogue params for this thread's 4 columns
  float4 sc = make_float4(1.f, 1.f, 1.f, 1.f);
  float4 sh = make_float4(0.f, 0.f, 0.f, 0.f);
  if (EPI == EPI_BNRELU || EPI == EPI_BNRELU_PREMUL) {
    float4 g = *(const float4*)&bng[c0];
    float4 b = *(const float4*)&bnb[c0];
    float4 m = *(const float4*)&bnm[c0];
    float4 v = *(const float4*)&bnv[c0];
    float4 bi = *(const float4*)&bias[c0];
    sc.x = g.x * rsqrtf(v.x + EPSF); sc.y = g.y * rsqrtf(v.y + EPSF);
    sc.z = g.z * rsqrtf(v.z + EPSF); sc.w = g.w * rsqrtf(v.w + EPSF);
    sh.x = b.x + (bi.x - m.x) * sc.x; sh.y = b.y + (bi.y - m.y) * sc.y;
    sh.z = b.z + (bi.z - m.z) * sc.z; sh.w = b.w + (bi.w - m.w) * sc.w;
  }
#pragma unroll
  for (int i = 0; i < RPT; ++i) {
    int gr = row0 + trow * RPT + i;
    if (gr >= NN) continue;
    float4 o;
    o.x = acc[i][0]; o.y = acc[i][1]; o.z = acc[i][2]; o.w = acc[i][3];
    if (EPI == EPI_BNRELU || EPI == EPI_BNRELU_PREMUL) {
      o.x = fmaxf(o.x * sc.x + sh.x, 0.f);
      o.y = fmaxf(o.y * sc.y + sh.y, 0.f);
      o.z = fmaxf(o.z * sc.z + sh.z, 0.f);
      o.w = fmaxf(o.w * sc.w + sh.w, 0.f);
    }
    if (EPI == EPI_BNRELU_PREMUL || EPI == EPI_PREMUL) {
      float d = dinv[gr];
      o.x *= d; o.y *= d; o.z *= d; o.w *= d;
    }
    *(float4*)&C[(size_t)gr * D + c0] = o;
  }
}

// ---------------- Pooling ----------------

__global__ void boundaries_k(const int* __restrict__ batch, int* __restrict__ start) {
  int i = blockIdx.x * blockDim.x + threadIdx.x;
  if (i >= NN) return;
  int b = batch[i];
  if (i == 0) {
    for (int g = 0; g <= b; ++g) start[g] = 0;
  } else {
    int p = batch[i - 1];
    for (int g = p + 1; g <= b; ++g) start[g] = i;
  }
  if (i == NN - 1) {
    for (int g = b + 1; g <= GG; ++g) start[g] = NN;
  }
}

__global__ __launch_bounds__(256) void pool_k(const float* __restrict__ ne,
                                              const int* __restrict__ start,
                                              float* __restrict__ ge) {
  __shared__ float red[256];
  int g = blockIdx.x;
  int tid = threadIdx.x;
  int c = tid & 63;
  int part = tid >> 6;
  int s = start[g], e = start[g + 1];
  float sum = 0.f;
  for (int i = s + part; i < e; i += 4) sum += ne[(size_t)i * 64 + c];
  red[tid] = sum;
  __syncthreads();
  if (part == 0) {
    float t = red[c] + red[c + 64] + red[c + 128] + red[c + 192];
    float cnt = (float)(e - s);
    ge[(size_t)g * 64 + c] = t / fmaxf(cnt, 1.f);
  }
}

// ---------------- launch ----------------

extern "C" void kernel_launch(void* const* d_in, const int* in_sizes, int n_in,
                              void* d_out, int out_size, void* d_ws, size_t ws_size,
                              hipStream_t stream) {
  const float* x = (const float*)d_in[0];
  const int* ei = (const int*)d_in[1];
  const int* srcv = ei;
  const int* dstv = ei + EE;
  const int* batch = (const int*)d_in[2];
  const float* W0 = (const float*)d_in[3];
  const float* b0 = (const float*)d_in[4];
  const float* W1 = (const float*)d_in[5];
  const float* b1 = (const float*)d_in[6];
  const float* W2 = (const float*)d_in[7];
  const float* b2 = (const float*)d_in[8];
  const float* bn0g = (const float*)d_in[9];
  const float* bn0b = (const float*)d_in[10];
  const float* bn0m = (const float*)d_in[11];
  const float* bn0v = (const float*)d_in[12];
  const float* bn1g = (const float*)d_in[13];
  const float* bn1b = (const float*)d_in[14];
  const float* bn1m = (const float*)d_in[15];
  const float* bn1v = (const float*)d_in[16];
  const float* lng = (const float*)d_in[17];
  const float* lnb = (const float*)d_in[18];

  float* out_nodes = (float*)d_out;
  float* out_graph = out_nodes + (size_t)NN * 64;

  char* ws = (char*)d_ws;
  size_t off = 0;
  auto carve = [&](size_t bytes) {
    void* p = ws + off;
    off = (off + bytes + 255) & ~(size_t)255;
    return p;
  };
  int* counts = (int*)carve((size_t)NN * 4);
  int* local_incl = (int*)carve((size_t)NN * 4);
  int* btot = (int*)carve(512 * 4);
  int* boff = (int*)carve(512 * 4);
  int* rowptr = (int*)carve((size_t)(NN + 1) * 4);
  int* cursor = (int*)carve((size_t)NN * 4);
  int* csr_src = (int*)carve((size_t)EE * 4);
  float* dinv = (float*)carve((size_t)NN * 4);
  int* gstart = (int*)carve((size_t)(GG + 1) * 4);
  float* bufA = (float*)carve((size_t)NN * 128 * 4);
  float* bufB = (float*)carve((size_t)NN * 128 * 4);

  hipMemsetAsync(counts, 0, (size_t)NN * 4, stream);

  int eg = (EE + 255) / 256;  // 6250
  int ng = NB;                // 391

  count_edges<<<eg, 256, 0, stream>>>(dstv, counts);
  block_scan<<<ng, 256, 0, stream>>>(counts, local_incl, btot);
  scan_totals<<<1, 512, 0, stream>>>(btot, boff);
  finalize_csr<<<ng, 256, 0, stream>>>(counts, local_incl, boff, rowptr, cursor, dinv);
  fill_csr<<<eg, 256, 0, stream>>>(srcv, dstv, cursor, csr_src);
  boundaries_k<<<ng, 256, 0, stream>>>(batch, gstart);

  int agrid = (NN + 3) / 4;      // 25000
  int ggrid = (NN + 63) / 64;    // 1563

  // xs = x * dinv  -> bufA[:, :64]
  premul_k<<<(NN * 16 + 255) / 256, 256, 0, stream>>>(x, dinv, bufA);
  // a0 = agg(xs) -> bufB   (64 ch)
  aggp64_k<<<agrid, 256, 0, stream>>>(bufA, rowptr, csr_src, dinv, bufB);
  // h0p = relu(BN(a0@W0 + b0)) * dinv -> bufA  (128 ch)
  gemm_k<64, 128, EPI_BNRELU_PREMUL><<<ggrid, 256, 0, stream>>>(
      bufB, W0, b0, bn0g, bn0b, bn0m, bn0v, dinv, bufA);
  // a1 = agg(h0p) -> bufB  (128 ch)
  aggp128_k<<<agrid, 256, 0, stream>>>(bufA, rowptr, csr_src, dinv, bufB);
  // h1 = relu(BN(a1@W1 + b1)) -> bufA  (128 ch, NOT premultiplied)
  gemm_k<128, 128, EPI_BNRELU><<<ggrid, 256, 0, stream>>>(
      bufB, W1, b1, bn1g, bn1b, bn1m, bn1v, dinv, bufA);
  // xw2p = (h1@W2) * dinv -> bufB  (64 ch; bias b2 applied post-agg)
  gemm_k<128, 64, EPI_PREMUL><<<ggrid, 256, 0, stream>>>(
      bufA, W2, b2, bn1g, bn1b, bn1m, bn1v, dinv, bufB);
  // out_nodes = LN(agg(xw2p) + b2)
  agg_ln_k<<<agrid, 256, 0, stream>>>(bufB, rowptr, csr_src, dinv, b2, lng, lnb,
                                      out_nodes);
  // graph mean pool
  pool_k<<<GG, 256, 0, stream>>>(out_nodes, gstart, out_graph);
}

// Round 4
// 541.041 us; speedup vs baseline: 2.5772x; 1.2573x over previous
//
#include <hip/hip_runtime.h>

#define NN 100000
#define EE 1600000
#define GG 64
#define EPSF 1e-5f
#define NB 391   // ceil(NN/256)
#define CAP 48   // CSR slots per node (Poisson(16); P(any overflow) ~ 6e-6)

// ---------------- bf16 helpers ----------------

__device__ __forceinline__ unsigned pack_bf16(float a, float b) {
  unsigned ua = __float_as_uint(a);
  unsigned ub = __float_as_uint(b);
  ua = (ua + 0x7fffu + ((ua >> 16) & 1u)) >> 16;           // RNE, low half
  ub = (ub + 0x7fffu + ((ub >> 16) & 1u)) & 0xffff0000u;   // RNE, high half
  return ua | ub;
}
__device__ __forceinline__ float blo(unsigned u) { return __uint_as_float(u << 16); }
__device__ __forceinline__ float bhi(unsigned u) { return __uint_as_float(u & 0xffff0000u); }

// ---------------- CSR build: fixed-cap slots, range-filtered passes ----------------

__global__ void fill_mp(const int* __restrict__ src, const int* __restrict__ dst,
                        int lo, int hi, int* __restrict__ cursor,
                        int* __restrict__ csr) {
  int e = blockIdx.x * 256 + threadIdx.x;
  if (e >= EE) return;
  int d = dst[e];
  if (d < lo || d >= hi) return;
  int pos = atomicAdd(&cursor[d], 1);
  if (pos < CAP) csr[d * CAP + pos] = src[e];
}

__global__ __launch_bounds__(256) void prep_k(const int* __restrict__ cursor,
                                              float* __restrict__ dinv) {
  int i = blockIdx.x * 256 + threadIdx.x;
  if (i < NN) dinv[i] = rsqrtf((float)cursor[i] + 1.0f);
}

// ---------------- premul: xs_bf16 = x * dinv[row] ----------------

__global__ __launch_bounds__(256) void premul_k(const float* __restrict__ x,
                                                const float* __restrict__ dinv,
                                                unsigned* __restrict__ xs) {
  int i = blockIdx.x * 256 + threadIdx.x;  // channel-pair index over NN*32
  if (i >= NN * 32) return;
  int n = i >> 5;
  float d = dinv[n];
  float2 v = ((const float2*)x)[i];
  xs[i] = pack_bf16(v.x * d, v.y * d);
}

// ---------------- Aggregation (bf16 in, fp32 accumulate) ----------------
// out[n] = dinv[n] * ( sum_{s} xp[s] + xp[n] ), xp premultiplied by dinv[s].

// 64-ch: one node per wave; half-wave per neighbor (2 neighbors per iteration).
__global__ __launch_bounds__(256) void aggp64_k(const unsigned* __restrict__ xp,
                                                const int* __restrict__ counts,
                                                const int* __restrict__ csr,
                                                const float* __restrict__ dinv,
                                                float* __restrict__ out) {
  int node = blockIdx.x * 4 + (threadIdx.x >> 6);
  if (node >= NN) return;
  int lane = threadIdx.x & 63;
  int half = lane >> 5, c = lane & 31;
  float2 acc = make_float2(0.f, 0.f);
  if (!half) {
    unsigned u = xp[(size_t)node * 32 + c];
    acc.x = blo(u); acc.y = bhi(u);
  }
  int cnt = min(counts[node], CAP);
  int base = node * CAP;
#pragma unroll 2
  for (int j = half; j < cnt; j += 2) {
    int s = csr[base + j];
    unsigned u = xp[(size_t)s * 32 + c];
    acc.x += blo(u); acc.y += bhi(u);
  }
  acc.x += __shfl_xor(acc.x, 32, 64);
  acc.y += __shfl_xor(acc.y, 32, 64);
  if (!half) {
    float di = dinv[node];
    ((float2*)out)[(size_t)node * 32 + c] = make_float2(acc.x * di, acc.y * di);
  }
}

// 128-ch: one node per wave, lane c holds channel pair (2c,2c+1); unroll-4 neighbors.
__global__ __launch_bounds__(256) void aggp128_k(const unsigned* __restrict__ xp,
                                                 const int* __restrict__ counts,
                                                 const int* __restrict__ csr,
                                                 const float* __restrict__ dinv,
                                                 float* __restrict__ out) {
  int node = blockIdx.x * 4 + (threadIdx.x >> 6);
  if (node >= NN) return;
  int c = threadIdx.x & 63;
  unsigned u = xp[(size_t)node * 64 + c];
  float2 acc = make_float2(blo(u), bhi(u));
  int cnt = min(counts[node], CAP);
  int base = node * CAP;
  int j = 0;
  for (; j + 4 <= cnt; j += 4) {
    int s0 = csr[base + j], s1 = csr[base + j + 1];
    int s2 = csr[base + j + 2], s3 = csr[base + j + 3];
    unsigned u0 = xp[(size_t)s0 * 64 + c];
    unsigned u1 = xp[(size_t)s1 * 64 + c];
    unsigned u2 = xp[(size_t)s2 * 64 + c];
    unsigned u3 = xp[(size_t)s3 * 64 + c];
    acc.x += (blo(u0) + blo(u1)) + (blo(u2) + blo(u3));
    acc.y += (bhi(u0) + bhi(u1)) + (bhi(u2) + bhi(u3));
  }
  for (; j < cnt; ++j) {
    unsigned uu = xp[(size_t)csr[base + j] * 64 + c];
    acc.x += blo(uu); acc.y += bhi(uu);
  }
  float di = dinv[node];
  ((float2*)out)[(size_t)node * 64 + c] = make_float2(acc.x * di, acc.y * di);
}

// final agg + bias + LayerNorm (bf16 in, fp32 out), same half-wave gather as aggp64.
__global__ __launch_bounds__(256) void agg_ln_k(const unsigned* __restrict__ xp,
                                                const int* __restrict__ counts,
                                                const int* __restrict__ csr,
                                                const float* __restrict__ dinv,
                                                const float* __restrict__ bias,
                                                const float* __restrict__ lng,
                                                const float* __restrict__ lnb,
                                                float* __restrict__ out) {
  int node = blockIdx.x * 4 + (threadIdx.x >> 6);
  if (node >= NN) return;
  int lane = threadIdx.x & 63;
  int half = lane >> 5, c = lane & 31;
  float2 acc = make_float2(0.f, 0.f);
  if (!half) {
    unsigned u = xp[(size_t)node * 32 + c];
    acc.x = blo(u); acc.y = bhi(u);
  }
  int cnt = min(counts[node], CAP);
  int base = node * CAP;
#pragma unroll 2
  for (int j = half; j < cnt; j += 2) {
    int s = csr[base + j];
    unsigned u = xp[(size_t)s * 32 + c];
    acc.x += blo(u); acc.y += bhi(u);
  }
  acc.x += __shfl_xor(acc.x, 32, 64);
  acc.y += __shfl_xor(acc.y, 32, 64);
  float di = dinv[node];
  float2 bi = ((const float2*)bias)[c];
  float vx = acc.x * di + bi.x;
  float vy = acc.y * di + bi.y;
  // LN over 64 channels: each 32-half independently holds all channels.
  float s = vx + vy;
#pragma unroll
  for (int off = 16; off > 0; off >>= 1) s += __shfl_xor(s, off, 64);
  float mu = s * (1.f / 64.f);
  float dx = vx - mu, dy = vy - mu;
  float vs = dx * dx + dy * dy;
#pragma unroll
  for (int off = 16; off > 0; off >>= 1) vs += __shfl_xor(vs, off, 64);
  float r = rsqrtf(vs * (1.f / 64.f) + EPSF);
  if (!half) {
    float2 g = ((const float2*)lng)[c];
    float2 b = ((const float2*)lnb)[c];
    ((float2*)out)[(size_t)node * 32 + c] =
        make_float2(dx * r * g.x + b.x, dy * r * g.y + b.y);
  }
}

// ---------------- GEMM: C[N,D] = A[N,K] @ W[K,D], fused epilogues ----------------

#define EPI_BNRELU 1
#define EPI_BNRELU_PREMUL 2
#define EPI_PREMUL 3

template <int K, int D, int EPI, bool BF16OUT>
__global__ __launch_bounds__(256, 2) void gemm_k(
    const float* __restrict__ A, const float* __restrict__ W,
    const float* __restrict__ bias, const float* __restrict__ bng,
    const float* __restrict__ bnb, const float* __restrict__ bnm,
    const float* __restrict__ bnv, const float* __restrict__ dinv,
    void* __restrict__ Cv) {
  constexpr int BM = 64, BK = 32;
  constexpr int CG = D / 4;
  constexpr int RG = 256 / CG;
  constexpr int RPT = BM / RG;
  __shared__ float sA[BM][BK + 4];
  __shared__ float sW[BK][D];
  int tid = threadIdx.x;
  int row0 = blockIdx.x * BM;
  int tc = tid % CG, trow = tid / CG;
  int c0 = tc * 4;
  float acc[RPT][4];
#pragma unroll
  for (int i = 0; i < RPT; ++i)
#pragma unroll
    for (int j = 0; j < 4; ++j) acc[i][j] = 0.f;

  for (int kk = 0; kk < K; kk += BK) {
#pragma unroll
    for (int t = 0; t < BM * BK / 1024; ++t) {
      int idx = tid + t * 256;
      int r = idx >> 3;
      int c4 = idx & 7;
      int gr = row0 + r;
      float4 v = make_float4(0.f, 0.f, 0.f, 0.f);
      if (gr < NN) v = *(const float4*)&A[(size_t)gr * K + kk + c4 * 4];
      *(float4*)&sA[r][c4 * 4] = v;
    }
#pragma unroll
    for (int t = 0; t < BK * D / 1024; ++t) {
      int idx = tid + t * 256;
      int r = idx / CG;
      int c4 = idx % CG;
      *(float4*)&sW[r][c4 * 4] = *(const float4*)&W[(size_t)(kk + r) * D + c4 * 4];
    }
    __syncthreads();
#pragma unroll 4
    for (int k = 0; k < BK; ++k) {
      float4 w = *(const float4*)&sW[k][c0];
#pragma unroll
      for (int i = 0; i < RPT; ++i) {
        float a = sA[trow * RPT + i][k];
        acc[i][0] += a * w.x;
        acc[i][1] += a * w.y;
        acc[i][2] += a * w.z;
        acc[i][3] += a * w.w;
      }
    }
    __syncthreads();
  }

  float4 sc = make_float4(1.f, 1.f, 1.f, 1.f);
  float4 sh = make_float4(0.f, 0.f, 0.f, 0.f);
  if (EPI == EPI_BNRELU || EPI == EPI_BNRELU_PREMUL) {
    float4 g = *(const float4*)&bng[c0];
    float4 b = *(const float4*)&bnb[c0];
    float4 m = *(const float4*)&bnm[c0];
    float4 v = *(const float4*)&bnv[c0];
    float4 bi = *(const float4*)&bias[c0];
    sc.x = g.x * rsqrtf(v.x + EPSF); sc.y = g.y * rsqrtf(v.y + EPSF);
    sc.z = g.z * rsqrtf(v.z + EPSF); sc.w = g.w * rsqrtf(v.w + EPSF);
    sh.x = b.x + (bi.x - m.x) * sc.x; sh.y = b.y + (bi.y - m.y) * sc.y;
    sh.z = b.z + (bi.z - m.z) * sc.z; sh.w = b.w + (bi.w - m.w) * sc.w;
  }
#pragma unroll
  for (int i = 0; i < RPT; ++i) {
    int gr = row0 + trow * RPT + i;
    if (gr >= NN) continue;
    float4 o;
    o.x = acc[i][0]; o.y = acc[i][1]; o.z = acc[i][2]; o.w = acc[i][3];
    if (EPI == EPI_BNRELU || EPI == EPI_BNRELU_PREMUL) {
      o.x = fmaxf(o.x * sc.x + sh.x, 0.f);
      o.y = fmaxf(o.y * sc.y + sh.y, 0.f);
      o.z = fmaxf(o.z * sc.z + sh.z, 0.f);
      o.w = fmaxf(o.w * sc.w + sh.w, 0.f);
    }
    if (EPI == EPI_BNRELU_PREMUL || EPI == EPI_PREMUL) {
      float d = dinv[gr];
      o.x *= d; o.y *= d; o.z *= d; o.w *= d;
    }
    if (BF16OUT) {
      uint2 p;
      p.x = pack_bf16(o.x, o.y);
      p.y = pack_bf16(o.z, o.w);
      *(uint2*)((unsigned short*)Cv + (size_t)gr * D + c0) = p;
    } else {
      *(float4*)&((float*)Cv)[(size_t)gr * D + c0] = o;
    }
  }
}

// ---------------- Pooling ----------------

__global__ void boundaries_k(const int* __restrict__ batch, int* __restrict__ start) {
  int i = blockIdx.x * blockDim.x + threadIdx.x;
  if (i >= NN) return;
  int b = batch[i];
  if (i == 0) {
    for (int g = 0; g <= b; ++g) start[g] = 0;
  } else {
    int p = batch[i - 1];
    for (int g = p + 1; g <= b; ++g) start[g] = i;
  }
  if (i == NN - 1) {
    for (int g = b + 1; g <= GG; ++g) start[g] = NN;
  }
}

__global__ __launch_bounds__(256) void pool_k(const float* __restrict__ ne,
                                              const int* __restrict__ start,
                                              float* __restrict__ ge) {
  __shared__ float red[256];
  int g = blockIdx.x;
  int tid = threadIdx.x;
  int c = tid & 63;
  int part = tid >> 6;
  int s = start[g], e = start[g + 1];
  float sum = 0.f;
  for (int i = s + part; i < e; i += 4) sum += ne[(size_t)i * 64 + c];
  red[tid] = sum;
  __syncthreads();
  if (part == 0) {
    float t = red[c] + red[c + 64] + red[c + 128] + red[c + 192];
    float cnt = (float)(e - s);
    ge[(size_t)g * 64 + c] = t / fmaxf(cnt, 1.f);
  }
}

// ---------------- launch ----------------

extern "C" void kernel_launch(void* const* d_in, const int* in_sizes, int n_in,
                              void* d_out, int out_size, void* d_ws, size_t ws_size,
                              hipStream_t stream) {
  const float* x = (const float*)d_in[0];
  const int* ei = (const int*)d_in[1];
  const int* srcv = ei;
  const int* dstv = ei + EE;
  const int* batch = (const int*)d_in[2];
  const float* W0 = (const float*)d_in[3];
  const float* b0 = (const float*)d_in[4];
  const float* W1 = (const float*)d_in[5];
  const float* b1 = (const float*)d_in[6];
  const float* W2 = (const float*)d_in[7];
  const float* b2 = (const float*)d_in[8];
  const float* bn0g = (const float*)d_in[9];
  const float* bn0b = (const float*)d_in[10];
  const float* bn0m = (const float*)d_in[11];
  const float* bn0v = (const float*)d_in[12];
  const float* bn1g = (const float*)d_in[13];
  const float* bn1b = (const float*)d_in[14];
  const float* bn1m = (const float*)d_in[15];
  const float* bn1v = (const float*)d_in[16];
  const float* lng = (const float*)d_in[17];
  const float* lnb = (const float*)d_in[18];

  float* out_nodes = (float*)d_out;
  float* out_graph = out_nodes + (size_t)NN * 64;

  char* ws = (char*)d_ws;
  size_t off = 0;
  auto carve = [&](size_t bytes) {
    void* p = ws + off;
    off = (off + bytes + 255) & ~(size_t)255;
    return p;
  };
  int* cursor = (int*)carve((size_t)NN * 4);          // doubles as counts
  float* dinv = (float*)carve((size_t)NN * 4);
  int* gstart = (int*)carve((size_t)(GG + 1) * 4);
  int* csr = (int*)carve((size_t)NN * CAP * 4);       // 19.2 MB
  void* bufA = carve((size_t)NN * 128 * 4);           // 51.2 MB
  void* bufB = carve((size_t)NN * 128 * 4);           // 51.2 MB

  hipMemsetAsync(cursor, 0, (size_t)NN * 4, stream);

  int eg = (EE + 255) / 256;  // 6250
  int ng = NB;                // 391

  // range-filtered CSR fill: 4 passes, each pass's active region cache-resident
  for (int p = 0; p < 4; ++p) {
    int lo = p * (NN / 4), hi = (p == 3) ? NN : (p + 1) * (NN / 4);
    fill_mp<<<eg, 256, 0, stream>>>(srcv, dstv, lo, hi, cursor, csr);
  }
  prep_k<<<ng, 256, 0, stream>>>(cursor, dinv);
  boundaries_k<<<ng, 256, 0, stream>>>(batch, gstart);

  int agrid = (NN + 3) / 4;    // 25000
  int ggrid = (NN + 63) / 64;  // 1563

  // xs_bf16 = x * dinv -> bufA
  premul_k<<<(NN * 32 + 255) / 256, 256, 0, stream>>>(x, dinv, (unsigned*)bufA);
  // a0 = agg(xs) -> bufB (fp32, 64ch)
  aggp64_k<<<agrid, 256, 0, stream>>>((const unsigned*)bufA, cursor, csr, dinv,
                                      (float*)bufB);
  // h0p_bf16 = relu(BN(a0@W0+b0)) * dinv -> bufA
  gemm_k<64, 128, EPI_BNRELU_PREMUL, true><<<ggrid, 256, 0, stream>>>(
      (const float*)bufB, W0, b0, bn0g, bn0b, bn0m, bn0v, dinv, bufA);
  // a1 = agg(h0p) -> bufB (fp32, 128ch)
  aggp128_k<<<agrid, 256, 0, stream>>>((const unsigned*)bufA, cursor, csr, dinv,
                                       (float*)bufB);
  // h1 = relu(BN(a1@W1+b1)) -> bufA (fp32)
  gemm_k<128, 128, EPI_BNRELU, false><<<ggrid, 256, 0, stream>>>(
      (const float*)bufB, W1, b1, bn1g, bn1b, bn1m, bn1v, dinv, bufA);
  // xw2p_bf16 = (h1@W2) * dinv -> bufB (bias b2 applied post-agg)
  gemm_k<128, 64, EPI_PREMUL, true><<<ggrid, 256, 0, stream>>>(
      (const float*)bufA, W2, b2, bn1g, bn1b, bn1m, bn1v, dinv, bufB);
  // out_nodes = LN(agg(xw2p) + b2)
  agg_ln_k<<<agrid, 256, 0, stream>>>((const unsigned*)bufB, cursor, csr, dinv, b2,
                                      lng, lnb, out_nodes);
  // graph mean pool
  pool_k<<<GG, 256, 0, stream>>>(out_nodes, gstart, out_graph);
}

// Round 5
// 458.119 us; speedup vs baseline: 3.0437x; 1.1810x over previous
//
#include <hip/hip_runtime.h>

#define NN 100000
#define EE 1600000
#define GG 64
#define EPSF 1e-5f
#define NB 391   // ceil(NN/256)
#define CAP 48   // CSR slots per node (Poisson(16); P(any overflow) ~ 6e-6)
#define PB 1024  // pool stage-1 blocks

// ---------------- bf16 helpers ----------------

__device__ __forceinline__ unsigned pack_bf16(float a, float b) {
  unsigned ua = __float_as_uint(a);
  unsigned ub = __float_as_uint(b);
  ua = (ua + 0x7fffu + ((ua >> 16) & 1u)) >> 16;           // RNE, low half
  ub = (ub + 0x7fffu + ((ub >> 16) & 1u)) & 0xffff0000u;   // RNE, high half
  return ua | ub;
}
__device__ __forceinline__ float blo(unsigned u) { return __uint_as_float(u << 16); }
__device__ __forceinline__ float bhi(unsigned u) { return __uint_as_float(u & 0xffff0000u); }

// ---------------- CSR build: fixed-cap slots, range-filtered passes ----------------

__global__ void fill_mp(const int* __restrict__ src, const int* __restrict__ dst,
                        int lo, int hi, int* __restrict__ cursor,
                        int* __restrict__ csr) {
  int e = blockIdx.x * 256 + threadIdx.x;
  if (e >= EE) return;
  int d = dst[e];
  if (d < lo || d >= hi) return;
  int pos = atomicAdd(&cursor[d], 1);
  if (pos < CAP) csr[d * CAP + pos] = src[e];
}

__global__ __launch_bounds__(256) void prep_k(const int* __restrict__ cursor,
                                              float* __restrict__ dinv) {
  int i = blockIdx.x * 256 + threadIdx.x;
  if (i < NN) dinv[i] = rsqrtf((float)cursor[i] + 1.0f);
}

// ---------------- premul: xs_bf16 = x * dinv[row] ----------------

__global__ __launch_bounds__(256) void premul_k(const float* __restrict__ x,
                                                const float* __restrict__ dinv,
                                                unsigned* __restrict__ xs) {
  int i = blockIdx.x * 256 + threadIdx.x;  // channel-pair index over NN*32
  if (i >= NN * 32) return;
  int n = i >> 5;
  float d = dinv[n];
  float2 v = ((const float2*)x)[i];
  xs[i] = pack_bf16(v.x * d, v.y * d);
}

// ---------------- Aggregation (bf16 in, fp32 accumulate) ----------------
// out[n] = dinv[n] * ( sum_{s} xp[s] + xp[n] ), xp premultiplied by dinv[s].

// 64-ch: one node per wave; half-wave per neighbor (2 neighbors per iteration).
__global__ __launch_bounds__(256) void aggp64_k(const unsigned* __restrict__ xp,
                                                const int* __restrict__ counts,
                                                const int* __restrict__ csr,
                                                const float* __restrict__ dinv,
                                                float* __restrict__ out) {
  int node = blockIdx.x * 4 + (threadIdx.x >> 6);
  if (node >= NN) return;
  int lane = threadIdx.x & 63;
  int half = lane >> 5, c = lane & 31;
  float2 acc = make_float2(0.f, 0.f);
  if (!half) {
    unsigned u = xp[(size_t)node * 32 + c];
    acc.x = blo(u); acc.y = bhi(u);
  }
  int cnt = min(counts[node], CAP);
  int base = node * CAP;
#pragma unroll 2
  for (int j = half; j < cnt; j += 2) {
    int s = csr[base + j];
    unsigned u = xp[(size_t)s * 32 + c];
    acc.x += blo(u); acc.y += bhi(u);
  }
  acc.x += __shfl_xor(acc.x, 32, 64);
  acc.y += __shfl_xor(acc.y, 32, 64);
  if (!half) {
    float di = dinv[node];
    ((float2*)out)[(size_t)node * 32 + c] = make_float2(acc.x * di, acc.y * di);
  }
}

// 128-ch: one node per wave, lane c holds channel pair (2c,2c+1); unroll-4 neighbors.
__global__ __launch_bounds__(256) void aggp128_k(const unsigned* __restrict__ xp,
                                                 const int* __restrict__ counts,
                                                 const int* __restrict__ csr,
                                                 const float* __restrict__ dinv,
                                                 float* __restrict__ out) {
  int node = blockIdx.x * 4 + (threadIdx.x >> 6);
  if (node >= NN) return;
  int c = threadIdx.x & 63;
  unsigned u = xp[(size_t)node * 64 + c];
  float2 acc = make_float2(blo(u), bhi(u));
  int cnt = min(counts[node], CAP);
  int base = node * CAP;
  int j = 0;
  for (; j + 4 <= cnt; j += 4) {
    int s0 = csr[base + j], s1 = csr[base + j + 1];
    int s2 = csr[base + j + 2], s3 = csr[base + j + 3];
    unsigned u0 = xp[(size_t)s0 * 64 + c];
    unsigned u1 = xp[(size_t)s1 * 64 + c];
    unsigned u2 = xp[(size_t)s2 * 64 + c];
    unsigned u3 = xp[(size_t)s3 * 64 + c];
    acc.x += (blo(u0) + blo(u1)) + (blo(u2) + blo(u3));
    acc.y += (bhi(u0) + bhi(u1)) + (bhi(u2) + bhi(u3));
  }
  for (; j < cnt; ++j) {
    unsigned uu = xp[(size_t)csr[base + j] * 64 + c];
    acc.x += blo(uu); acc.y += bhi(uu);
  }
  float di = dinv[node];
  ((float2*)out)[(size_t)node * 64 + c] = make_float2(acc.x * di, acc.y * di);
}

// final agg + bias + LayerNorm (bf16 in, fp32 out), same half-wave gather as aggp64.
__global__ __launch_bounds__(256) void agg_ln_k(const unsigned* __restrict__ xp,
                                                const int* __restrict__ counts,
                                                const int* __restrict__ csr,
                                                const float* __restrict__ dinv,
                                                const float* __restrict__ bias,
                                                const float* __restrict__ lng,
                                                const float* __restrict__ lnb,
                                                float* __restrict__ out) {
  int node = blockIdx.x * 4 + (threadIdx.x >> 6);
  if (node >= NN) return;
  int lane = threadIdx.x & 63;
  int half = lane >> 5, c = lane & 31;
  float2 acc = make_float2(0.f, 0.f);
  if (!half) {
    unsigned u = xp[(size_t)node * 32 + c];
    acc.x = blo(u); acc.y = bhi(u);
  }
  int cnt = min(counts[node], CAP);
  int base = node * CAP;
#pragma unroll 2
  for (int j = half; j < cnt; j += 2) {
    int s = csr[base + j];
    unsigned u = xp[(size_t)s * 32 + c];
    acc.x += blo(u); acc.y += bhi(u);
  }
  acc.x += __shfl_xor(acc.x, 32, 64);
  acc.y += __shfl_xor(acc.y, 32, 64);
  float di = dinv[node];
  float2 bi = ((const float2*)bias)[c];
  float vx = acc.x * di + bi.x;
  float vy = acc.y * di + bi.y;
  // LN over 64 channels: each 32-half independently holds all channels.
  float s = vx + vy;
#pragma unroll
  for (int off = 16; off > 0; off >>= 1) s += __shfl_xor(s, off, 64);
  float mu = s * (1.f / 64.f);
  float dx = vx - mu, dy = vy - mu;
  float vs = dx * dx + dy * dy;
#pragma unroll
  for (int off = 16; off > 0; off >>= 1) vs += __shfl_xor(vs, off, 64);
  float r = rsqrtf(vs * (1.f / 64.f) + EPSF);
  if (!half) {
    float2 g = ((const float2*)lng)[c];
    float2 b = ((const float2*)lnb)[c];
    ((float2*)out)[(size_t)node * 32 + c] =
        make_float2(dx * r * g.x + b.x, dy * r * g.y + b.y);
  }
}

// ---------------- GEMM: C[N,D] = A[N,K] @ W[K,D], fused epilogues ----------------

#define EPI_BNRELU 1
#define EPI_BNRELU_PREMUL 2
#define EPI_PREMUL 3

template <int K, int D, int EPI, bool BF16OUT>
__global__ __launch_bounds__(256, 2) void gemm_k(
    const float* __restrict__ A, const float* __restrict__ W,
    const float* __restrict__ bias, const float* __restrict__ bng,
    const float* __restrict__ bnb, const float* __restrict__ bnm,
    const float* __restrict__ bnv, const float* __restrict__ dinv,
    void* __restrict__ Cv) {
  constexpr int BM = 64, BK = 32;
  constexpr int CG = D / 4;
  constexpr int RG = 256 / CG;
  constexpr int RPT = BM / RG;
  __shared__ float sA[BM][BK + 4];
  __shared__ float sW[BK][D];
  int tid = threadIdx.x;
  int row0 = blockIdx.x * BM;
  int tc = tid % CG, trow = tid / CG;
  int c0 = tc * 4;
  float acc[RPT][4];
#pragma unroll
  for (int i = 0; i < RPT; ++i)
#pragma unroll
    for (int j = 0; j < 4; ++j) acc[i][j] = 0.f;

  for (int kk = 0; kk < K; kk += BK) {
#pragma unroll
    for (int t = 0; t < BM * BK / 1024; ++t) {
      int idx = tid + t * 256;
      int r = idx >> 3;
      int c4 = idx & 7;
      int gr = row0 + r;
      float4 v = make_float4(0.f, 0.f, 0.f, 0.f);
      if (gr < NN) v = *(const float4*)&A[(size_t)gr * K + kk + c4 * 4];
      *(float4*)&sA[r][c4 * 4] = v;
    }
#pragma unroll
    for (int t = 0; t < BK * D / 1024; ++t) {
      int idx = tid + t * 256;
      int r = idx / CG;
      int c4 = idx % CG;
      *(float4*)&sW[r][c4 * 4] = *(const float4*)&W[(size_t)(kk + r) * D + c4 * 4];
    }
    __syncthreads();
#pragma unroll 4
    for (int k = 0; k < BK; ++k) {
      float4 w = *(const float4*)&sW[k][c0];
#pragma unroll
      for (int i = 0; i < RPT; ++i) {
        float a = sA[trow * RPT + i][k];
        acc[i][0] += a * w.x;
        acc[i][1] += a * w.y;
        acc[i][2] += a * w.z;
        acc[i][3] += a * w.w;
      }
    }
    __syncthreads();
  }

  float4 sc = make_float4(1.f, 1.f, 1.f, 1.f);
  float4 sh = make_float4(0.f, 0.f, 0.f, 0.f);
  if (EPI == EPI_BNRELU || EPI == EPI_BNRELU_PREMUL) {
    float4 g = *(const float4*)&bng[c0];
    float4 b = *(const float4*)&bnb[c0];
    float4 m = *(const float4*)&bnm[c0];
    float4 v = *(const float4*)&bnv[c0];
    float4 bi = *(const float4*)&bias[c0];
    sc.x = g.x * rsqrtf(v.x + EPSF); sc.y = g.y * rsqrtf(v.y + EPSF);
    sc.z = g.z * rsqrtf(v.z + EPSF); sc.w = g.w * rsqrtf(v.w + EPSF);
    sh.x = b.x + (bi.x - m.x) * sc.x; sh.y = b.y + (bi.y - m.y) * sc.y;
    sh.z = b.z + (bi.z - m.z) * sc.z; sh.w = b.w + (bi.w - m.w) * sc.w;
  }
#pragma unroll
  for (int i = 0; i < RPT; ++i) {
    int gr = row0 + trow * RPT + i;
    if (gr >= NN) continue;
    float4 o;
    o.x = acc[i][0]; o.y = acc[i][1]; o.z = acc[i][2]; o.w = acc[i][3];
    if (EPI == EPI_BNRELU || EPI == EPI_BNRELU_PREMUL) {
      o.x = fmaxf(o.x * sc.x + sh.x, 0.f);
      o.y = fmaxf(o.y * sc.y + sh.y, 0.f);
      o.z = fmaxf(o.z * sc.z + sh.z, 0.f);
      o.w = fmaxf(o.w * sc.w + sh.w, 0.f);
    }
    if (EPI == EPI_BNRELU_PREMUL || EPI == EPI_PREMUL) {
      float d = dinv[gr];
      o.x *= d; o.y *= d; o.z *= d; o.w *= d;
    }
    if (BF16OUT) {
      uint2 p;
      p.x = pack_bf16(o.x, o.y);
      p.y = pack_bf16(o.z, o.w);
      *(uint2*)((unsigned short*)Cv + (size_t)gr * D + c0) = p;
    } else {
      *(float4*)&((float*)Cv)[(size_t)gr * D + c0] = o;
    }
  }
}

// ---------------- Pooling (two-stage) ----------------

__global__ void boundaries_k(const int* __restrict__ batch, int* __restrict__ start) {
  int i = blockIdx.x * blockDim.x + threadIdx.x;
  if (i >= NN) return;
  int b = batch[i];
  if (i == 0) {
    for (int g = 0; g <= b; ++g) start[g] = 0;
  } else {
    int p = batch[i - 1];
    for (int g = p + 1; g <= b; ++g) start[g] = i;
  }
  if (i == NN - 1) {
    for (int g = b + 1; g <= GG; ++g) start[g] = NN;
  }
}

// stage 1: each block owns a contiguous node chunk; per-thread local accumulation
// with flush-on-graph-change (batch is sorted -> ~1-2 flushes per thread).
__global__ __launch_bounds__(256) void pool1_k(const float* __restrict__ ne,
                                               const int* __restrict__ batch,
                                               float* __restrict__ acc) {
  const int CHUNK = (NN + PB - 1) / PB;  // 98
  int i0 = blockIdx.x * CHUNK;
  int i1 = min(i0 + CHUNK, NN);
  if (i0 >= NN) return;
  int c = threadIdx.x & 63;
  int part = threadIdx.x >> 6;  // 0..3
  int cur = -1;
  float a = 0.f;
  for (int i = i0 + part; i < i1; i += 4) {
    int b = batch[i];  // wave-uniform (all lanes of a wave share i)
    if (b != cur) {
      if (cur >= 0) atomicAdd(&acc[cur * 64 + c], a);
      cur = b;
      a = 0.f;
    }
    a += ne[(size_t)i * 64 + c];
  }
  if (cur >= 0) atomicAdd(&acc[cur * 64 + c], a);
}

// stage 2: divide by per-graph counts
__global__ __launch_bounds__(256) void pool2_k(const float* __restrict__ acc,
                                               const int* __restrict__ start,
                                               float* __restrict__ ge) {
  int i = blockIdx.x * 256 + threadIdx.x;
  if (i >= GG * 64) return;
  int g = i >> 6;
  float cnt = (float)(start[g + 1] - start[g]);
  ge[i] = acc[i] / fmaxf(cnt, 1.f);
}

// ---------------- launch ----------------

extern "C" void kernel_launch(void* const* d_in, const int* in_sizes, int n_in,
                              void* d_out, int out_size, void* d_ws, size_t ws_size,
                              hipStream_t stream) {
  const float* x = (const float*)d_in[0];
  const int* ei = (const int*)d_in[1];
  const int* srcv = ei;
  const int* dstv = ei + EE;
  const int* batch = (const int*)d_in[2];
  const float* W0 = (const float*)d_in[3];
  const float* b0 = (const float*)d_in[4];
  const float* W1 = (const float*)d_in[5];
  const float* b1 = (const float*)d_in[6];
  const float* W2 = (const float*)d_in[7];
  const float* b2 = (const float*)d_in[8];
  const float* bn0g = (const float*)d_in[9];
  const float* bn0b = (const float*)d_in[10];
  const float* bn0m = (const float*)d_in[11];
  const float* bn0v = (const float*)d_in[12];
  const float* bn1g = (const float*)d_in[13];
  const float* bn1b = (const float*)d_in[14];
  const float* bn1m = (const float*)d_in[15];
  const float* bn1v = (const float*)d_in[16];
  const float* lng = (const float*)d_in[17];
  const float* lnb = (const float*)d_in[18];

  float* out_nodes = (float*)d_out;
  float* out_graph = out_nodes + (size_t)NN * 64;

  char* ws = (char*)d_ws;
  size_t off = 0;
  auto carve = [&](size_t bytes) {
    void* p = ws + off;
    off = (off + bytes + 255) & ~(size_t)255;
    return p;
  };
  int* cursor = (int*)carve((size_t)NN * 4);          // doubles as counts
  float* dinv = (float*)carve((size_t)NN * 4);
  int* gstart = (int*)carve((size_t)(GG + 1) * 4);
  float* pacc = (float*)carve((size_t)GG * 64 * 4);   // pool accumulator
  int* csr = (int*)carve((size_t)NN * CAP * 4);       // 19.2 MB
  void* bufA = carve((size_t)NN * 128 * 4);           // 51.2 MB
  void* bufB = carve((size_t)NN * 128 * 4);           // 51.2 MB

  hipMemsetAsync(cursor, 0, (size_t)NN * 4, stream);
  hipMemsetAsync(pacc, 0, (size_t)GG * 64 * 4, stream);

  int eg = (EE + 255) / 256;  // 6250
  int ng = NB;                // 391

  // range-filtered CSR fill: 4 passes, each pass's active region cache-resident
  for (int p = 0; p < 4; ++p) {
    int lo = p * (NN / 4), hi = (p == 3) ? NN : (p + 1) * (NN / 4);
    fill_mp<<<eg, 256, 0, stream>>>(srcv, dstv, lo, hi, cursor, csr);
  }
  prep_k<<<ng, 256, 0, stream>>>(cursor, dinv);
  boundaries_k<<<ng, 256, 0, stream>>>(batch, gstart);

  int agrid = (NN + 3) / 4;    // 25000
  int ggrid = (NN + 63) / 64;  // 1563

  // xs_bf16 = x * dinv -> bufA
  premul_k<<<(NN * 32 + 255) / 256, 256, 0, stream>>>(x, dinv, (unsigned*)bufA);
  // a0 = agg(xs) -> bufB (fp32, 64ch)
  aggp64_k<<<agrid, 256, 0, stream>>>((const unsigned*)bufA, cursor, csr, dinv,
                                      (float*)bufB);
  // h0p_bf16 = relu(BN(a0@W0+b0)) * dinv -> bufA
  gemm_k<64, 128, EPI_BNRELU_PREMUL, true><<<ggrid, 256, 0, stream>>>(
      (const float*)bufB, W0, b0, bn0g, bn0b, bn0m, bn0v, dinv, bufA);
  // a1 = agg(h0p) -> bufB (fp32, 128ch)
  aggp128_k<<<agrid, 256, 0, stream>>>((const unsigned*)bufA, cursor, csr, dinv,
                                       (float*)bufB);
  // h1 = relu(BN(a1@W1+b1)) -> bufA (fp32)
  gemm_k<128, 128, EPI_BNRELU, false><<<ggrid, 256, 0, stream>>>(
      (const float*)bufB, W1, b1, bn1g, bn1b, bn1m, bn1v, dinv, bufA);
  // xw2p_bf16 = (h1@W2) * dinv -> bufB (bias b2 applied post-agg)
  gemm_k<128, 64, EPI_PREMUL, true><<<ggrid, 256, 0, stream>>>(
      (const float*)bufA, W2, b2, bn1g, bn1b, bn1m, bn1v, dinv, bufB);
  // out_nodes = LN(agg(xw2p) + b2)
  agg_ln_k<<<agrid, 256, 0, stream>>>((const unsigned*)bufB, cursor, csr, dinv, b2,
                                      lng, lnb, out_nodes);
  // two-stage graph mean pool
  pool1_k<<<PB, 256, 0, stream>>>(out_nodes, batch, pacc);
  pool2_k<<<(GG * 64 + 255) / 256, 256, 0, stream>>>(pacc, gstart, out_graph);
}

// Round 6
// 409.863 us; speedup vs baseline: 3.4021x; 1.1177x over previous
//
#include <hip/hip_runtime.h>

#define NN 100000
#define EE 1600000
#define GG 64
#define EPSF 1e-5f
#define NB 391   // ceil(NN/256)
#define CAP 48   // CSR slots per node (Poisson(16); P(any overflow) ~ 6e-6)
#define PB 1024  // pool stage-1 blocks

typedef short short8 __attribute__((ext_vector_type(8)));
typedef float f32x4 __attribute__((ext_vector_type(4)));

// ---------------- bf16 helpers ----------------

__device__ __forceinline__ unsigned pack_bf16(float a, float b) {
  unsigned ua = __float_as_uint(a);
  unsigned ub = __float_as_uint(b);
  ua = (ua + 0x7fffu + ((ua >> 16) & 1u)) >> 16;           // RNE, low half
  ub = (ub + 0x7fffu + ((ub >> 16) & 1u)) & 0xffff0000u;   // RNE, high half
  return ua | ub;
}
__device__ __forceinline__ unsigned short bf16_1(float a) {
  unsigned u = __float_as_uint(a);
  return (unsigned short)((u + 0x7fffu + ((u >> 16) & 1u)) >> 16);
}
__device__ __forceinline__ float blo(unsigned u) { return __uint_as_float(u << 16); }
__device__ __forceinline__ float bhi(unsigned u) { return __uint_as_float(u & 0xffff0000u); }

// ---------------- CSR build: fixed-cap slots, range-filtered passes ----------------

__global__ void fill_mp(const int* __restrict__ src, const int* __restrict__ dst,
                        int lo, int hi, int* __restrict__ cursor,
                        int* __restrict__ csr) {
  int e = blockIdx.x * 256 + threadIdx.x;
  if (e >= EE) return;
  int d = dst[e];
  if (d < lo || d >= hi) return;
  int pos = atomicAdd(&cursor[d], 1);
  if (pos < CAP) csr[d * CAP + pos] = src[e];
}

__global__ __launch_bounds__(256) void prep_k(const int* __restrict__ cursor,
                                              float* __restrict__ dinv) {
  int i = blockIdx.x * 256 + threadIdx.x;
  if (i < NN) dinv[i] = rsqrtf((float)cursor[i] + 1.0f);
}

// ---------------- weight prep: transpose + bf16; BN scale/shift ----------------

__global__ __launch_bounds__(256) void wprep_k(
    const float* __restrict__ W0, const float* __restrict__ W1,
    const float* __restrict__ W2, unsigned short* __restrict__ wt0,
    unsigned short* __restrict__ wt1, unsigned short* __restrict__ wt2) {
  int i = blockIdx.x * 256 + threadIdx.x;
  if (i < 8192) {                       // Wt0 [128][64]
    int d = i >> 6, k = i & 63;
    wt0[d * 64 + k] = bf16_1(W0[k * 128 + d]);
  } else if (i < 24576) {               // Wt1 [128][128]
    int j = i - 8192;
    int d = j >> 7, k = j & 127;
    wt1[d * 128 + k] = bf16_1(W1[k * 128 + d]);
  } else if (i < 32768) {               // Wt2 [64][128]
    int j = i - 24576;
    int d = j >> 7, k = j & 127;
    wt2[d * 128 + k] = bf16_1(W2[k * 64 + d]);
  }
}

__global__ void bnprep_k(const float* __restrict__ b0, const float* __restrict__ g0,
                         const float* __restrict__ be0, const float* __restrict__ m0,
                         const float* __restrict__ v0, const float* __restrict__ b1,
                         const float* __restrict__ g1, const float* __restrict__ be1,
                         const float* __restrict__ m1, const float* __restrict__ v1,
                         float* __restrict__ s0, float* __restrict__ h0,
                         float* __restrict__ s1, float* __restrict__ h1) {
  int i = threadIdx.x;
  if (i < 128) {
    float s = g0[i] * rsqrtf(v0[i] + EPSF);
    s0[i] = s;
    h0[i] = be0[i] + (b0[i] - m0[i]) * s;
  } else {
    int j = i - 128;
    float s = g1[j] * rsqrtf(v1[j] + EPSF);
    s1[j] = s;
    h1[j] = be1[j] + (b1[j] - m1[j]) * s;
  }
}

// ---------------- premul: xs_bf16 = x * dinv[row] ----------------

__global__ __launch_bounds__(256) void premul_k(const float* __restrict__ x,
                                                const float* __restrict__ dinv,
                                                unsigned* __restrict__ xs) {
  int i = blockIdx.x * 256 + threadIdx.x;  // channel-pair index over NN*32
  if (i >= NN * 32) return;
  int n = i >> 5;
  float d = dinv[n];
  float2 v = ((const float2*)x)[i];
  xs[i] = pack_bf16(v.x * d, v.y * d);
}

// ---------------- Aggregation (bf16 in, fp32 accumulate, bf16 out) ----------------
// out[n] = dinv[n] * ( sum_{s} xp[s] + xp[n] ), xp premultiplied by dinv[s].

// 64-ch: one node per wave; half-wave per neighbor (2 neighbors per iteration).
__global__ __launch_bounds__(256) void aggp64_k(const unsigned* __restrict__ xp,
                                                const int* __restrict__ counts,
                                                const int* __restrict__ csr,
                                                const float* __restrict__ dinv,
                                                unsigned* __restrict__ out) {
  int node = blockIdx.x * 4 + (threadIdx.x >> 6);
  if (node >= NN) return;
  int lane = threadIdx.x & 63;
  int half = lane >> 5, c = lane & 31;
  float2 acc = make_float2(0.f, 0.f);
  if (!half) {
    unsigned u = xp[(size_t)node * 32 + c];
    acc.x = blo(u); acc.y = bhi(u);
  }
  int cnt = min(counts[node], CAP);
  int base = node * CAP;
#pragma unroll 2
  for (int j = half; j < cnt; j += 2) {
    int s = csr[base + j];
    unsigned u = xp[(size_t)s * 32 + c];
    acc.x += blo(u); acc.y += bhi(u);
  }
  acc.x += __shfl_xor(acc.x, 32, 64);
  acc.y += __shfl_xor(acc.y, 32, 64);
  if (!half) {
    float di = dinv[node];
    out[(size_t)node * 32 + c] = pack_bf16(acc.x * di, acc.y * di);
  }
}

// 128-ch: one node per wave, lane c holds channel pair (2c,2c+1); unroll-4 neighbors.
__global__ __launch_bounds__(256) void aggp128_k(const unsigned* __restrict__ xp,
                                                 const int* __restrict__ counts,
                                                 const int* __restrict__ csr,
                                                 const float* __restrict__ dinv,
                                                 unsigned* __restrict__ out) {
  int node = blockIdx.x * 4 + (threadIdx.x >> 6);
  if (node >= NN) return;
  int c = threadIdx.x & 63;
  unsigned u = xp[(size_t)node * 64 + c];
  float2 acc = make_float2(blo(u), bhi(u));
  int cnt = min(counts[node], CAP);
  int base = node * CAP;
  int j = 0;
  for (; j + 4 <= cnt; j += 4) {
    int s0 = csr[base + j], s1 = csr[base + j + 1];
    int s2 = csr[base + j + 2], s3 = csr[base + j + 3];
    unsigned u0 = xp[(size_t)s0 * 64 + c];
    unsigned u1 = xp[(size_t)s1 * 64 + c];
    unsigned u2 = xp[(size_t)s2 * 64 + c];
    unsigned u3 = xp[(size_t)s3 * 64 + c];
    acc.x += (blo(u0) + blo(u1)) + (blo(u2) + blo(u3));
    acc.y += (bhi(u0) + bhi(u1)) + (bhi(u2) + bhi(u3));
  }
  for (; j < cnt; ++j) {
    unsigned uu = xp[(size_t)csr[base + j] * 64 + c];
    acc.x += blo(uu); acc.y += bhi(uu);
  }
  float di = dinv[node];
  out[(size_t)node * 64 + c] = pack_bf16(acc.x * di, acc.y * di);
}

// final agg + bias + LayerNorm (bf16 in, fp32 out), half-wave gather.
__global__ __launch_bounds__(256) void agg_ln_k(const unsigned* __restrict__ xp,
                                                const int* __restrict__ counts,
                                                const int* __restrict__ csr,
                                                const float* __restrict__ dinv,
                                                const float* __restrict__ bias,
                                                const float* __restrict__ lng,
                                                const float* __restrict__ lnb,
                                                float* __restrict__ out) {
  int node = blockIdx.x * 4 + (threadIdx.x >> 6);
  if (node >= NN) return;
  int lane = threadIdx.x & 63;
  int half = lane >> 5, c = lane & 31;
  float2 acc = make_float2(0.f, 0.f);
  if (!half) {
    unsigned u = xp[(size_t)node * 32 + c];
    acc.x = blo(u); acc.y = bhi(u);
  }
  int cnt = min(counts[node], CAP);
  int base = node * CAP;
#pragma unroll 2
  for (int j = half; j < cnt; j += 2) {
    int s = csr[base + j];
    unsigned u = xp[(size_t)s * 32 + c];
    acc.x += blo(u); acc.y += bhi(u);
  }
  acc.x += __shfl_xor(acc.x, 32, 64);
  acc.y += __shfl_xor(acc.y, 32, 64);
  float di = dinv[node];
  float2 bi = ((const float2*)bias)[c];
  float vx = acc.x * di + bi.x;
  float vy = acc.y * di + bi.y;
  float s = vx + vy;
#pragma unroll
  for (int off = 16; off > 0; off >>= 1) s += __shfl_xor(s, off, 64);
  float mu = s * (1.f / 64.f);
  float dx = vx - mu, dy = vy - mu;
  float vs = dx * dx + dy * dy;
#pragma unroll
  for (int off = 16; off > 0; off >>= 1) vs += __shfl_xor(vs, off, 64);
  float r = rsqrtf(vs * (1.f / 64.f) + EPSF);
  if (!half) {
    float2 g = ((const float2*)lng)[c];
    float2 b = ((const float2*)lnb)[c];
    ((float2*)out)[(size_t)node * 32 + c] =
        make_float2(dx * r * g.x + b.x, dy * r * g.y + b.y);
  }
}

// ---------------- MFMA GEMM: C[N,D] = A[N,K] @ W[K,D], bf16 in/out ----------------
// 4 waves/block, BM=64 rows (16/wave). A staged [64][K+8] LDS; Wt [D][K+8] LDS.
// mfma_f32_16x16x32_bf16: A-frag row=lane&15,k=(lane>>4)*8+j; C/D col=lane&15,
// row=(lane>>4)*4+reg (guide-verified layouts).

#define EPI_BNRELU 1
#define EPI_BNRELU_PREMUL 2
#define EPI_PREMUL 3

template <int K, int D, int EPI>
__global__ __launch_bounds__(256, 2) void gemm_mfma_k(
    const unsigned short* __restrict__ Abf,   // [N][K] bf16
    const unsigned short* __restrict__ Wt,    // [D][K] bf16 (pre-transposed)
    const float* __restrict__ scale,          // [D]
    const float* __restrict__ shift,          // [D]
    const float* __restrict__ dinv,
    unsigned short* __restrict__ C) {         // [N][D] bf16
  constexpr int BM = 64;
  constexpr int LK = K + 8;                   // +16B pad: 2-way bank alias (free)
  constexpr int NT = D / 16;
  __shared__ unsigned short sA[BM * LK];
  __shared__ unsigned short sW[D * LK];
  int tid = threadIdx.x;
  int row0 = blockIdx.x * BM;
  // stage A (16B chunks, coalesced)
  for (int i = tid; i < BM * K / 8; i += 256) {
    int r = i / (K / 8), c8 = i % (K / 8);
    int gr = row0 + r;
    short8 v = {};
    if (gr < NN) v = *(const short8*)&Abf[(size_t)gr * K + c8 * 8];
    *(short8*)&sA[r * LK + c8 * 8] = v;
  }
  // stage Wt (L2-resident across blocks)
  for (int i = tid; i < D * K / 8; i += 256) {
    int d = i / (K / 8), c8 = i % (K / 8);
    *(short8*)&sW[d * LK + c8 * 8] = *(const short8*)&Wt[d * K + c8 * 8];
  }
  __syncthreads();
  int wid = tid >> 6, lane = tid & 63;
  int lr = lane & 15, kg = lane >> 4;
  f32x4 acc[NT];
#pragma unroll
  for (int t = 0; t < NT; ++t) acc[t] = (f32x4){0.f, 0.f, 0.f, 0.f};
  const unsigned short* pa = &sA[(wid * 16 + lr) * LK + kg * 8];
#pragma unroll
  for (int kk = 0; kk < K / 32; ++kk) {
    short8 a = *(const short8*)(pa + kk * 32);
#pragma unroll
    for (int t = 0; t < NT; ++t) {
      short8 b = *(const short8*)&sW[(t * 16 + lr) * LK + kk * 32 + kg * 8];
      acc[t] = __builtin_amdgcn_mfma_f32_16x16x32_bf16(a, b, acc[t], 0, 0, 0);
    }
  }
  // epilogue: col = t*16 + lr; rows = row0 + wid*16 + kg*4 + j
  int rbase = row0 + wid * 16 + kg * 4;
  float dv[4];
  if (EPI != EPI_BNRELU) {
#pragma unroll
    for (int j = 0; j < 4; ++j) dv[j] = (rbase + j < NN) ? dinv[rbase + j] : 0.f;
  }
#pragma unroll
  for (int t = 0; t < NT; ++t) {
    int col = t * 16 + lr;
    float sc = 1.f, sh = 0.f;
    if (EPI != EPI_PREMUL) { sc = scale[col]; sh = shift[col]; }
#pragma unroll
    for (int j = 0; j < 4; ++j) {
      int r = rbase + j;
      if (r >= NN) continue;
      float v = acc[t][j];
      if (EPI != EPI_PREMUL) v = fmaxf(v * sc + sh, 0.f);
      if (EPI != EPI_BNRELU) v *= dv[j];
      C[(size_t)r * D + col] = bf16_1(v);
    }
  }
}

// ---------------- Pooling (two-stage) ----------------

__global__ void boundaries_k(const int* __restrict__ batch, int* __restrict__ start) {
  int i = blockIdx.x * blockDim.x + threadIdx.x;
  if (i >= NN) return;
  int b = batch[i];
  if (i == 0) {
    for (int g = 0; g <= b; ++g) start[g] = 0;
  } else {
    int p = batch[i - 1];
    for (int g = p + 1; g <= b; ++g) start[g] = i;
  }
  if (i == NN - 1) {
    for (int g = b + 1; g <= GG; ++g) start[g] = NN;
  }
}

__global__ __launch_bounds__(256) void pool1_k(const float* __restrict__ ne,
                                               const int* __restrict__ batch,
                                               float* __restrict__ acc) {
  const int CHUNK = (NN + PB - 1) / PB;  // 98
  int i0 = blockIdx.x * CHUNK;
  int i1 = min(i0 + CHUNK, NN);
  if (i0 >= NN) return;
  int c = threadIdx.x & 63;
  int part = threadIdx.x >> 6;  // 0..3
  int cur = -1;
  float a = 0.f;
  for (int i = i0 + part; i < i1; i += 4) {
    int b = batch[i];  // wave-uniform
    if (b != cur) {
      if (cur >= 0) atomicAdd(&acc[cur * 64 + c], a);
      cur = b;
      a = 0.f;
    }
    a += ne[(size_t)i * 64 + c];
  }
  if (cur >= 0) atomicAdd(&acc[cur * 64 + c], a);
}

__global__ __launch_bounds__(256) void pool2_k(const float* __restrict__ acc,
                                               const int* __restrict__ start,
                                               float* __restrict__ ge) {
  int i = blockIdx.x * 256 + threadIdx.x;
  if (i >= GG * 64) return;
  int g = i >> 6;
  float cnt = (float)(start[g + 1] - start[g]);
  ge[i] = acc[i] / fmaxf(cnt, 1.f);
}

// ---------------- launch ----------------

extern "C" void kernel_launch(void* const* d_in, const int* in_sizes, int n_in,
                              void* d_out, int out_size, void* d_ws, size_t ws_size,
                              hipStream_t stream) {
  const float* x = (const float*)d_in[0];
  const int* ei = (const int*)d_in[1];
  const int* srcv = ei;
  const int* dstv = ei + EE;
  const int* batch = (const int*)d_in[2];
  const float* W0 = (const float*)d_in[3];
  const float* b0 = (const float*)d_in[4];
  const float* W1 = (const float*)d_in[5];
  const float* b1 = (const float*)d_in[6];
  const float* W2 = (const float*)d_in[7];
  const float* b2 = (const float*)d_in[8];
  const float* bn0g = (const float*)d_in[9];
  const float* bn0b = (const float*)d_in[10];
  const float* bn0m = (const float*)d_in[11];
  const float* bn0v = (const float*)d_in[12];
  const float* bn1g = (const float*)d_in[13];
  const float* bn1b = (const float*)d_in[14];
  const float* bn1m = (const float*)d_in[15];
  const float* bn1v = (const float*)d_in[16];
  const float* lng = (const float*)d_in[17];
  const float* lnb = (const float*)d_in[18];

  float* out_nodes = (float*)d_out;
  float* out_graph = out_nodes + (size_t)NN * 64;

  char* ws = (char*)d_ws;
  size_t off = 0;
  auto carve = [&](size_t bytes) {
    void* p = ws + off;
    off = (off + bytes + 255) & ~(size_t)255;
    return p;
  };
  int* cursor = (int*)carve((size_t)NN * 4);          // doubles as counts
  float* dinv = (float*)carve((size_t)NN * 4);
  int* gstart = (int*)carve((size_t)(GG + 1) * 4);
  float* pacc = (float*)carve((size_t)GG * 64 * 4);
  unsigned short* wt0 = (unsigned short*)carve(8192 * 2);    // [128][64]
  unsigned short* wt1 = (unsigned short*)carve(16384 * 2);   // [128][128]
  unsigned short* wt2 = (unsigned short*)carve(8192 * 2);    // [64][128]
  float* s0 = (float*)carve(128 * 4);
  float* h0 = (float*)carve(128 * 4);
  float* s1 = (float*)carve(128 * 4);
  float* h1 = (float*)carve(128 * 4);
  int* csr = (int*)carve((size_t)NN * CAP * 4);       // 19.2 MB
  void* bufA = carve((size_t)NN * 128 * 4);
  void* bufB = carve((size_t)NN * 128 * 4);

  hipMemsetAsync(cursor, 0, (size_t)NN * 4, stream);
  hipMemsetAsync(pacc, 0, (size_t)GG * 64 * 4, stream);

  int eg = (EE + 255) / 256;  // 6250
  int ng = NB;                // 391

  wprep_k<<<128, 256, 0, stream>>>(W0, W1, W2, wt0, wt1, wt2);
  bnprep_k<<<1, 256, 0, stream>>>(b0, bn0g, bn0b, bn0m, bn0v,
                                  b1, bn1g, bn1b, bn1m, bn1v, s0, h0, s1, h1);
  // range-filtered CSR fill: 4 passes
  for (int p = 0; p < 4; ++p) {
    int lo = p * (NN / 4), hi = (p == 3) ? NN : (p + 1) * (NN / 4);
    fill_mp<<<eg, 256, 0, stream>>>(srcv, dstv, lo, hi, cursor, csr);
  }
  prep_k<<<ng, 256, 0, stream>>>(cursor, dinv);
  boundaries_k<<<ng, 256, 0, stream>>>(batch, gstart);

  int agrid = (NN + 3) / 4;    // 25000
  int mgrid = (NN + 63) / 64;  // 1563

  // xs_bf16 = x * dinv -> bufA
  premul_k<<<(NN * 32 + 255) / 256, 256, 0, stream>>>(x, dinv, (unsigned*)bufA);
  // a0 = agg(xs) -> bufB (bf16, 64ch)
  aggp64_k<<<agrid, 256, 0, stream>>>((const unsigned*)bufA, cursor, csr, dinv,
                                      (unsigned*)bufB);
  // h0p = relu(bn(a0@W0)) * dinv -> bufA (bf16, 128ch)
  gemm_mfma_k<64, 128, EPI_BNRELU_PREMUL><<<mgrid, 256, 0, stream>>>(
      (const unsigned short*)bufB, wt0, s0, h0, dinv, (unsigned short*)bufA);
  // a1 = agg(h0p) -> bufB (bf16, 128ch)
  aggp128_k<<<agrid, 256, 0, stream>>>((const unsigned*)bufA, cursor, csr, dinv,
                                       (unsigned*)bufB);
  // h1 = relu(bn(a1@W1)) -> bufA (bf16, 128ch)
  gemm_mfma_k<128, 128, EPI_BNRELU><<<mgrid, 256, 0, stream>>>(
      (const unsigned short*)bufB, wt1, s1, h1, dinv, (unsigned short*)bufA);
  // xw2p = (h1@W2) * dinv -> bufB (bf16, 64ch; bias b2 post-agg)
  gemm_mfma_k<128, 64, EPI_PREMUL><<<mgrid, 256, 0, stream>>>(
      (const unsigned short*)bufA, wt2, s1, h1, dinv, (unsigned short*)bufB);
  // out_nodes = LN(agg(xw2p) + b2)
  agg_ln_k<<<agrid, 256, 0, stream>>>((const unsigned*)bufB, cursor, csr, dinv, b2,
                                      lng, lnb, out_nodes);
  // two-stage graph mean pool
  pool1_k<<<PB, 256, 0, stream>>>(out_nodes, batch, pacc);
  pool2_k<<<(GG * 64 + 255) / 256, 256, 0, stream>>>(pacc, gstart, out_graph);
}

// Round 7
// 366.493 us; speedup vs baseline: 3.8047x; 1.1183x over previous
//
#include <hip/hip_runtime.h>

#define NN 100000
#define EE 1600000
#define GG 64
#define EPSF 1e-5f
#define NB 391   // ceil(NN/256)
#define CAP 48   // CSR slots per node (Poisson(16); P(any overflow) ~ 6e-6)
#define PB 1024  // pool stage-1 blocks

typedef short short8 __attribute__((ext_vector_type(8)));
typedef float f32x4 __attribute__((ext_vector_type(4)));

// ---------------- bf16 helpers ----------------

__device__ __forceinline__ unsigned pack_bf16(float a, float b) {
  unsigned ua = __float_as_uint(a);
  unsigned ub = __float_as_uint(b);
  ua = (ua + 0x7fffu + ((ua >> 16) & 1u)) >> 16;           // RNE, low half
  ub = (ub + 0x7fffu + ((ub >> 16) & 1u)) & 0xffff0000u;   // RNE, high half
  return ua | ub;
}
__device__ __forceinline__ unsigned short bf16_1(float a) {
  unsigned u = __float_as_uint(a);
  return (unsigned short)((u + 0x7fffu + ((u >> 16) & 1u)) >> 16);
}
__device__ __forceinline__ float blo(unsigned u) { return __uint_as_float(u << 16); }
__device__ __forceinline__ float bhi(unsigned u) { return __uint_as_float(u & 0xffff0000u); }

__device__ __forceinline__ void acc_u4(float* a, uint4 u) {
  a[0] += blo(u.x); a[1] += bhi(u.x);
  a[2] += blo(u.y); a[3] += bhi(u.y);
  a[4] += blo(u.z); a[5] += bhi(u.z);
  a[6] += blo(u.w); a[7] += bhi(u.w);
}

// ---------------- CSR build: fixed-cap slots, range-filtered passes ----------------

__global__ void fill_mp(const int* __restrict__ src, const int* __restrict__ dst,
                        int lo, int hi, int* __restrict__ cursor,
                        int* __restrict__ csr) {
  int e = blockIdx.x * 256 + threadIdx.x;
  if (e >= EE) return;
  int d = dst[e];
  if (d < lo || d >= hi) return;
  int pos = atomicAdd(&cursor[d], 1);
  if (pos < CAP) csr[d * CAP + pos] = src[e];
}

__global__ __launch_bounds__(256) void prep_k(const int* __restrict__ cursor,
                                              float* __restrict__ dinv) {
  int i = blockIdx.x * 256 + threadIdx.x;
  if (i < NN) dinv[i] = rsqrtf((float)cursor[i] + 1.0f);
}

// ---------------- weight prep: transpose + bf16; BN scale/shift ----------------

__global__ __launch_bounds__(256) void wprep_k(
    const float* __restrict__ W0, const float* __restrict__ W1,
    const float* __restrict__ W2, unsigned short* __restrict__ wt0,
    unsigned short* __restrict__ wt1, unsigned short* __restrict__ wt2) {
  int i = blockIdx.x * 256 + threadIdx.x;
  if (i < 8192) {                       // Wt0 [128][64]
    int d = i >> 6, k = i & 63;
    wt0[d * 64 + k] = bf16_1(W0[k * 128 + d]);
  } else if (i < 24576) {               // Wt1 [128][128]
    int j = i - 8192;
    int d = j >> 7, k = j & 127;
    wt1[d * 128 + k] = bf16_1(W1[k * 128 + d]);
  } else if (i < 32768) {               // Wt2 [64][128]
    int j = i - 24576;
    int d = j >> 7, k = j & 127;
    wt2[d * 128 + k] = bf16_1(W2[k * 64 + d]);
  }
}

__global__ void bnprep_k(const float* __restrict__ b0, const float* __restrict__ g0,
                         const float* __restrict__ be0, const float* __restrict__ m0,
                         const float* __restrict__ v0, const float* __restrict__ b1,
                         const float* __restrict__ g1, const float* __restrict__ be1,
                         const float* __restrict__ m1, const float* __restrict__ v1,
                         float* __restrict__ s0, float* __restrict__ h0,
                         float* __restrict__ s1, float* __restrict__ h1) {
  int i = threadIdx.x;
  if (i < 128) {
    float s = g0[i] * rsqrtf(v0[i] + EPSF);
    s0[i] = s;
    h0[i] = be0[i] + (b0[i] - m0[i]) * s;
  } else {
    int j = i - 128;
    float s = g1[j] * rsqrtf(v1[j] + EPSF);
    s1[j] = s;
    h1[j] = be1[j] + (b1[j] - m1[j]) * s;
  }
}

// ---------------- premul: xs_bf16 = x * dinv[row] ----------------

__global__ __launch_bounds__(256) void premul_k(const float* __restrict__ x,
                                                const float* __restrict__ dinv,
                                                unsigned* __restrict__ xs) {
  int i = blockIdx.x * 256 + threadIdx.x;  // channel-pair index over NN*32
  if (i >= NN * 32) return;
  int n = i >> 5;
  float d = dinv[n];
  float2 v = ((const float2*)x)[i];
  xs[i] = pack_bf16(v.x * d, v.y * d);
}

// ---------------- Aggregation (bf16 in, fp32 accumulate, bf16 out) ----------------
// out[n] = dinv[n] * ( sum_{s} xp[s] + xp[n] ), xp premultiplied by dinv[s].
// 16B/lane gathers: sub-wave group per edge, multiple rows per load instruction.

// 64-ch: row = 128B = 8 lanes x uint4. 8 edges per load instruction.
__global__ __launch_bounds__(256) void aggp64_k(const uint4* __restrict__ xp4,
                                                const int* __restrict__ counts,
                                                const int* __restrict__ csr,
                                                const float* __restrict__ dinv,
                                                uint4* __restrict__ out4) {
  int node = blockIdx.x * 4 + (threadIdx.x >> 6);
  if (node >= NN) return;
  int lane = threadIdx.x & 63;
  int g = lane >> 3, sl = lane & 7;
  float a[8] = {0.f, 0.f, 0.f, 0.f, 0.f, 0.f, 0.f, 0.f};
  if (g == 0) acc_u4(a, xp4[(size_t)node * 8 + sl]);  // self term
  int cnt = min(counts[node], CAP);
  int base = node * CAP;
  for (int j = g; j < cnt; j += 8) {
    int s = csr[base + j];
    acc_u4(a, xp4[(size_t)s * 8 + sl]);
  }
#pragma unroll
  for (int i = 0; i < 8; ++i) {
    a[i] += __shfl_xor(a[i], 8, 64);
    a[i] += __shfl_xor(a[i], 16, 64);
    a[i] += __shfl_xor(a[i], 32, 64);
  }
  if (g == 0) {
    float di = dinv[node];
    uint4 o;
    o.x = pack_bf16(a[0] * di, a[1] * di);
    o.y = pack_bf16(a[2] * di, a[3] * di);
    o.z = pack_bf16(a[4] * di, a[5] * di);
    o.w = pack_bf16(a[6] * di, a[7] * di);
    out4[(size_t)node * 8 + sl] = o;
  }
}

// 128-ch: row = 256B = 16 lanes x uint4. 4 edges per load instruction, unroll 2.
__global__ __launch_bounds__(256) void aggp128_k(const uint4* __restrict__ xp4,
                                                 const int* __restrict__ counts,
                                                 const int* __restrict__ csr,
                                                 const float* __restrict__ dinv,
                                                 uint4* __restrict__ out4) {
  int node = blockIdx.x * 4 + (threadIdx.x >> 6);
  if (node >= NN) return;
  int lane = threadIdx.x & 63;
  int q = lane >> 4, sl = lane & 15;
  float a[8] = {0.f, 0.f, 0.f, 0.f, 0.f, 0.f, 0.f, 0.f};
  if (q == 0) acc_u4(a, xp4[(size_t)node * 16 + sl]);  // self term
  int cnt = min(counts[node], CAP);
  int base = node * CAP;
  int j = q;
  for (; j + 4 < cnt; j += 8) {
    int s0 = csr[base + j];
    int s1 = csr[base + j + 4];
    uint4 u0 = xp4[(size_t)s0 * 16 + sl];
    uint4 u1 = xp4[(size_t)s1 * 16 + sl];
    acc_u4(a, u0);
    acc_u4(a, u1);
  }
  if (j < cnt) acc_u4(a, xp4[(size_t)csr[base + j] * 16 + sl]);
#pragma unroll
  for (int i = 0; i < 8; ++i) {
    a[i] += __shfl_xor(a[i], 16, 64);
    a[i] += __shfl_xor(a[i], 32, 64);
  }
  if (q == 0) {
    float di = dinv[node];
    uint4 o;
    o.x = pack_bf16(a[0] * di, a[1] * di);
    o.y = pack_bf16(a[2] * di, a[3] * di);
    o.z = pack_bf16(a[4] * di, a[5] * di);
    o.w = pack_bf16(a[6] * di, a[7] * di);
    out4[(size_t)node * 16 + sl] = o;
  }
}

// final agg + bias + LayerNorm (64-ch bf16 in, fp32 out), eighth-wave gather.
__global__ __launch_bounds__(256) void agg_ln_k(const uint4* __restrict__ xp4,
                                                const int* __restrict__ counts,
                                                const int* __restrict__ csr,
                                                const float* __restrict__ dinv,
                                                const float* __restrict__ bias,
                                                const float* __restrict__ lng,
                                                const float* __restrict__ lnb,
                                                float* __restrict__ out) {
  int node = blockIdx.x * 4 + (threadIdx.x >> 6);
  if (node >= NN) return;
  int lane = threadIdx.x & 63;
  int g = lane >> 3, sl = lane & 7;
  float a[8] = {0.f, 0.f, 0.f, 0.f, 0.f, 0.f, 0.f, 0.f};
  if (g == 0) acc_u4(a, xp4[(size_t)node * 8 + sl]);  // self term
  int cnt = min(counts[node], CAP);
  int base = node * CAP;
  for (int j = g; j < cnt; j += 8) {
    int s = csr[base + j];
    acc_u4(a, xp4[(size_t)s * 8 + sl]);
  }
#pragma unroll
  for (int i = 0; i < 8; ++i) {
    a[i] += __shfl_xor(a[i], 8, 64);
    a[i] += __shfl_xor(a[i], 16, 64);
    a[i] += __shfl_xor(a[i], 32, 64);
  }
  // all lanes now hold channels sl*8..sl*8+7
  float di = dinv[node];
  float4 b0 = ((const float4*)bias)[sl * 2];
  float4 b1 = ((const float4*)bias)[sl * 2 + 1];
  float v[8];
  v[0] = a[0] * di + b0.x; v[1] = a[1] * di + b0.y;
  v[2] = a[2] * di + b0.z; v[3] = a[3] * di + b0.w;
  v[4] = a[4] * di + b1.x; v[5] = a[5] * di + b1.y;
  v[6] = a[6] * di + b1.z; v[7] = a[7] * di + b1.w;
  float s = ((v[0] + v[1]) + (v[2] + v[3])) + ((v[4] + v[5]) + (v[6] + v[7]));
#pragma unroll
  for (int off = 1; off < 8; off <<= 1) s += __shfl_xor(s, off, 64);
  float mu = s * (1.f / 64.f);
  float vs = 0.f;
#pragma unroll
  for (int i = 0; i < 8; ++i) {
    v[i] -= mu;
    vs += v[i] * v[i];
  }
#pragma unroll
  for (int off = 1; off < 8; off <<= 1) vs += __shfl_xor(vs, off, 64);
  float r = rsqrtf(vs * (1.f / 64.f) + EPSF);
  if (g == 0) {
    float4 g0 = ((const float4*)lng)[sl * 2];
    float4 g1 = ((const float4*)lng)[sl * 2 + 1];
    float4 e0 = ((const float4*)lnb)[sl * 2];
    float4 e1 = ((const float4*)lnb)[sl * 2 + 1];
    float4 o0, o1;
    o0.x = v[0] * r * g0.x + e0.x; o0.y = v[1] * r * g0.y + e0.y;
    o0.z = v[2] * r * g0.z + e0.z; o0.w = v[3] * r * g0.w + e0.w;
    o1.x = v[4] * r * g1.x + e1.x; o1.y = v[5] * r * g1.y + e1.y;
    o1.z = v[6] * r * g1.z + e1.z; o1.w = v[7] * r * g1.w + e1.w;
    ((float4*)out)[(size_t)node * 16 + sl * 2] = o0;
    ((float4*)out)[(size_t)node * 16 + sl * 2 + 1] = o1;
  }
}

// ---------------- MFMA GEMM: C[N,D] = A[N,K] @ W[K,D], bf16 in/out ----------------

#define EPI_BNRELU 1
#define EPI_BNRELU_PREMUL 2
#define EPI_PREMUL 3

template <int K, int D, int EPI>
__global__ __launch_bounds__(256, 2) void gemm_mfma_k(
    const unsigned short* __restrict__ Abf,   // [N][K] bf16
    const unsigned short* __restrict__ Wt,    // [D][K] bf16 (pre-transposed)
    const float* __restrict__ scale,          // [D]
    const float* __restrict__ shift,          // [D]
    const float* __restrict__ dinv,
    unsigned short* __restrict__ C) {         // [N][D] bf16
  constexpr int BM = 64;
  constexpr int LK = K + 8;                   // +16B pad: 2-way bank alias (free)
  constexpr int NT = D / 16;
  __shared__ unsigned short sA[BM * LK];
  __shared__ unsigned short sW[D * LK];
  int tid = threadIdx.x;
  int row0 = blockIdx.x * BM;
  for (int i = tid; i < BM * K / 8; i += 256) {
    int r = i / (K / 8), c8 = i % (K / 8);
    int gr = row0 + r;
    short8 v = {};
    if (gr < NN) v = *(const short8*)&Abf[(size_t)gr * K + c8 * 8];
    *(short8*)&sA[r * LK + c8 * 8] = v;
  }
  for (int i = tid; i < D * K / 8; i += 256) {
    int d = i / (K / 8), c8 = i % (K / 8);
    *(short8*)&sW[d * LK + c8 * 8] = *(const short8*)&Wt[d * K + c8 * 8];
  }
  __syncthreads();
  int wid = tid >> 6, lane = tid & 63;
  int lr = lane & 15, kg = lane >> 4;
  f32x4 acc[NT];
#pragma unroll
  for (int t = 0; t < NT; ++t) acc[t] = (f32x4){0.f, 0.f, 0.f, 0.f};
  const unsigned short* pa = &sA[(wid * 16 + lr) * LK + kg * 8];
#pragma unroll
  for (int kk = 0; kk < K / 32; ++kk) {
    short8 a = *(const short8*)(pa + kk * 32);
#pragma unroll
    for (int t = 0; t < NT; ++t) {
      short8 b = *(const short8*)&sW[(t * 16 + lr) * LK + kk * 32 + kg * 8];
      acc[t] = __builtin_amdgcn_mfma_f32_16x16x32_bf16(a, b, acc[t], 0, 0, 0);
    }
  }
  int rbase = row0 + wid * 16 + kg * 4;
  float dv[4];
  if (EPI != EPI_BNRELU) {
#pragma unroll
    for (int j = 0; j < 4; ++j) dv[j] = (rbase + j < NN) ? dinv[rbase + j] : 0.f;
  }
#pragma unroll
  for (int t = 0; t < NT; ++t) {
    int col = t * 16 + lr;
    float sc = 1.f, sh = 0.f;
    if (EPI != EPI_PREMUL) { sc = scale[col]; sh = shift[col]; }
#pragma unroll
    for (int j = 0; j < 4; ++j) {
      int r = rbase + j;
      if (r >= NN) continue;
      float v = acc[t][j];
      if (EPI != EPI_PREMUL) v = fmaxf(v * sc + sh, 0.f);
      if (EPI != EPI_BNRELU) v *= dv[j];
      C[(size_t)r * D + col] = bf16_1(v);
    }
  }
}

// ---------------- Pooling (two-stage) ----------------

__global__ void boundaries_k(const int* __restrict__ batch, int* __restrict__ start) {
  int i = blockIdx.x * blockDim.x + threadIdx.x;
  if (i >= NN) return;
  int b = batch[i];
  if (i == 0) {
    for (int g = 0; g <= b; ++g) start[g] = 0;
  } else {
    int p = batch[i - 1];
    for (int g = p + 1; g <= b; ++g) start[g] = i;
  }
  if (i == NN - 1) {
    for (int g = b + 1; g <= GG; ++g) start[g] = NN;
  }
}

__global__ __launch_bounds__(256) void pool1_k(const float* __restrict__ ne,
                                               const int* __restrict__ batch,
                                               float* __restrict__ acc) {
  const int CHUNK = (NN + PB - 1) / PB;  // 98
  int i0 = blockIdx.x * CHUNK;
  int i1 = min(i0 + CHUNK, NN);
  if (i0 >= NN) return;
  int c = threadIdx.x & 63;
  int part = threadIdx.x >> 6;  // 0..3
  int cur = -1;
  float a = 0.f;
  for (int i = i0 + part; i < i1; i += 4) {
    int b = batch[i];  // wave-uniform
    if (b != cur) {
      if (cur >= 0) atomicAdd(&acc[cur * 64 + c], a);
      cur = b;
      a = 0.f;
    }
    a += ne[(size_t)i * 64 + c];
  }
  if (cur >= 0) atomicAdd(&acc[cur * 64 + c], a);
}

__global__ __launch_bounds__(256) void pool2_k(const float* __restrict__ acc,
                                               const int* __restrict__ start,
                                               float* __restrict__ ge) {
  int i = blockIdx.x * 256 + threadIdx.x;
  if (i >= GG * 64) return;
  int g = i >> 6;
  float cnt = (float)(start[g + 1] - start[g]);
  ge[i] = acc[i] / fmaxf(cnt, 1.f);
}

// ---------------- launch ----------------

extern "C" void kernel_launch(void* const* d_in, const int* in_sizes, int n_in,
                              void* d_out, int out_size, void* d_ws, size_t ws_size,
                              hipStream_t stream) {
  const float* x = (const float*)d_in[0];
  const int* ei = (const int*)d_in[1];
  const int* srcv = ei;
  const int* dstv = ei + EE;
  const int* batch = (const int*)d_in[2];
  const float* W0 = (const float*)d_in[3];
  const float* b0 = (const float*)d_in[4];
  const float* W1 = (const float*)d_in[5];
  const float* b1 = (const float*)d_in[6];
  const float* W2 = (const float*)d_in[7];
  const float* b2 = (const float*)d_in[8];
  const float* bn0g = (const float*)d_in[9];
  const float* bn0b = (const float*)d_in[10];
  const float* bn0m = (const float*)d_in[11];
  const float* bn0v = (const float*)d_in[12];
  const float* bn1g = (const float*)d_in[13];
  const float* bn1b = (const float*)d_in[14];
  const float* bn1m = (const float*)d_in[15];
  const float* bn1v = (const float*)d_in[16];
  const float* lng = (const float*)d_in[17];
  const float* lnb = (const float*)d_in[18];

  float* out_nodes = (float*)d_out;
  float* out_graph = out_nodes + (size_t)NN * 64;

  char* ws = (char*)d_ws;
  size_t off = 0;
  auto carve = [&](size_t bytes) {
    void* p = ws + off;
    off = (off + bytes + 255) & ~(size_t)255;
    return p;
  };
  int* cursor = (int*)carve((size_t)NN * 4);          // doubles as counts
  float* dinv = (float*)carve((size_t)NN * 4);
  int* gstart = (int*)carve((size_t)(GG + 1) * 4);
  float* pacc = (float*)carve((size_t)GG * 64 * 4);
  unsigned short* wt0 = (unsigned short*)carve(8192 * 2);    // [128][64]
  unsigned short* wt1 = (unsigned short*)carve(16384 * 2);   // [128][128]
  unsigned short* wt2 = (unsigned short*)carve(8192 * 2);    // [64][128]
  float* s0 = (float*)carve(128 * 4);
  float* h0 = (float*)carve(128 * 4);
  float* s1 = (float*)carve(128 * 4);
  float* h1 = (float*)carve(128 * 4);
  int* csr = (int*)carve((size_t)NN * CAP * 4);       // 19.2 MB
  void* bufA = carve((size_t)NN * 128 * 4);
  void* bufB = carve((size_t)NN * 128 * 4);

  hipMemsetAsync(cursor, 0, (size_t)NN * 4, stream);
  hipMemsetAsync(pacc, 0, (size_t)GG * 64 * 4, stream);

  int eg = (EE + 255) / 256;  // 6250
  int ng = NB;                // 391

  wprep_k<<<128, 256, 0, stream>>>(W0, W1, W2, wt0, wt1, wt2);
  bnprep_k<<<1, 256, 0, stream>>>(b0, bn0g, bn0b, bn0m, bn0v,
                                  b1, bn1g, bn1b, bn1m, bn1v, s0, h0, s1, h1);
  for (int p = 0; p < 4; ++p) {
    int lo = p * (NN / 4), hi = (p == 3) ? NN : (p + 1) * (NN / 4);
    fill_mp<<<eg, 256, 0, stream>>>(srcv, dstv, lo, hi, cursor, csr);
  }
  prep_k<<<ng, 256, 0, stream>>>(cursor, dinv);
  boundaries_k<<<ng, 256, 0, stream>>>(batch, gstart);

  int agrid = (NN + 3) / 4;    // 25000
  int mgrid = (NN + 63) / 64;  // 1563

  // xs_bf16 = x * dinv -> bufA
  premul_k<<<(NN * 32 + 255) / 256, 256, 0, stream>>>(x, dinv, (unsigned*)bufA);
  // a0 = agg(xs) -> bufB (bf16, 64ch)
  aggp64_k<<<agrid, 256, 0, stream>>>((const uint4*)bufA, cursor, csr, dinv,
                                      (uint4*)bufB);
  // h0p = relu(bn(a0@W0)) * dinv -> bufA (bf16, 128ch)
  gemm_mfma_k<64, 128, EPI_BNRELU_PREMUL><<<mgrid, 256, 0, stream>>>(
      (const unsigned short*)bufB, wt0, s0, h0, dinv, (unsigned short*)bufA);
  // a1 = agg(h0p) -> bufB (bf16, 128ch)
  aggp128_k<<<agrid, 256, 0, stream>>>((const uint4*)bufA, cursor, csr, dinv,
                                       (uint4*)bufB);
  // h1 = relu(bn(a1@W1)) -> bufA (bf16, 128ch)
  gemm_mfma_k<128, 128, EPI_BNRELU><<<mgrid, 256, 0, stream>>>(
      (const unsigned short*)bufB, wt1, s1, h1, dinv, (unsigned short*)bufA);
  // xw2p = (h1@W2) * dinv -> bufB (bf16, 64ch; bias b2 post-agg)
  gemm_mfma_k<128, 64, EPI_PREMUL><<<mgrid, 256, 0, stream>>>(
      (const unsigned short*)bufA, wt2, s1, h1, dinv, (unsigned short*)bufB);
  // out_nodes = LN(agg(xw2p) + b2)
  agg_ln_k<<<agrid, 256, 0, stream>>>((const uint4*)bufB, cursor, csr, dinv, b2,
                                      lng, lnb, out_nodes);
  // two-stage graph mean pool
  pool1_k<<<PB, 256, 0, stream>>>(out_nodes, batch, pacc);
  pool2_k<<<(GG * 64 + 255) / 256, 256, 0, stream>>>(pacc, gstart, out_graph);
}

// Round 9
// 356.417 us; speedup vs baseline: 3.9122x; 1.0283x over previous
//
#include <hip/hip_runtime.h>

#define NN 100000
#define EE 1600000
#define GG 64
#define EPSF 1e-5f
#define NB 391   // ceil(NN/256)
#define CAP 48   // CSR slots per node (Poisson(16); P(any overflow) ~ 6e-6)
#define PB 1024  // pool stage-1 blocks

typedef short short8 __attribute__((ext_vector_type(8)));
typedef float f32x4 __attribute__((ext_vector_type(4)));

// ---------------- bf16 helpers ----------------

__device__ __forceinline__ unsigned pack_bf16(float a, float b) {
  unsigned ua = __float_as_uint(a);
  unsigned ub = __float_as_uint(b);
  ua = (ua + 0x7fffu + ((ua >> 16) & 1u)) >> 16;           // RNE, low half
  ub = (ub + 0x7fffu + ((ub >> 16) & 1u)) & 0xffff0000u;   // RNE, high half
  return ua | ub;
}
__device__ __forceinline__ unsigned short bf16_1(float a) {
  unsigned u = __float_as_uint(a);
  return (unsigned short)((u + 0x7fffu + ((u >> 16) & 1u)) >> 16);
}
__device__ __forceinline__ float blo(unsigned u) { return __uint_as_float(u << 16); }
__device__ __forceinline__ float bhi(unsigned u) { return __uint_as_float(u & 0xffff0000u); }

__device__ __forceinline__ void acc_u4(float* a, uint4 u) {
  a[0] += blo(u.x); a[1] += bhi(u.x);
  a[2] += blo(u.y); a[3] += bhi(u.y);
  a[4] += blo(u.z); a[5] += bhi(u.z);
  a[6] += blo(u.w); a[7] += bhi(u.w);
}

// ---------------- CSR build: fixed-cap slots, range-filtered passes ----------------

__global__ void fill_mp(const int* __restrict__ src, const int* __restrict__ dst,
                        int lo, int hi, int* __restrict__ cursor,
                        int* __restrict__ csr) {
  int e = blockIdx.x * 256 + threadIdx.x;
  if (e >= EE) return;
  int d = dst[e];
  if (d < lo || d >= hi) return;
  int pos = atomicAdd(&cursor[d], 1);
  if (pos < CAP) csr[d * CAP + pos] = src[e];
}

__global__ __launch_bounds__(256) void prep_k(const int* __restrict__ cursor,
                                              float* __restrict__ dinv) {
  int i = blockIdx.x * 256 + threadIdx.x;
  if (i < NN) dinv[i] = rsqrtf((float)cursor[i] + 1.0f);
}

// ---------------- weight prep: transpose + bf16; BN scale/shift ----------------

__global__ __launch_bounds__(256) void wprep_k(
    const float* __restrict__ W0, const float* __restrict__ W1,
    const float* __restrict__ W2, unsigned short* __restrict__ wt0,
    unsigned short* __restrict__ wt1, unsigned short* __restrict__ wt2) {
  int i = blockIdx.x * 256 + threadIdx.x;
  if (i < 8192) {                       // Wt0 [128][64]
    int d = i >> 6, k = i & 63;
    wt0[d * 64 + k] = bf16_1(W0[k * 128 + d]);
  } else if (i < 24576) {               // Wt1 [128][128]
    int j = i - 8192;
    int d = j >> 7, k = j & 127;
    wt1[d * 128 + k] = bf16_1(W1[k * 128 + d]);
  } else if (i < 32768) {               // Wt2 [64][128]
    int j = i - 24576;
    int d = j >> 7, k = j & 127;
    wt2[d * 128 + k] = bf16_1(W2[k * 64 + d]);
  }
}

__global__ void bnprep_k(const float* __restrict__ b0, const float* __restrict__ g0,
                         const float* __restrict__ be0, const float* __restrict__ m0,
                         const float* __restrict__ v0, const float* __restrict__ b1,
                         const float* __restrict__ g1, const float* __restrict__ be1,
                         const float* __restrict__ m1, const float* __restrict__ v1,
                         float* __restrict__ s0, float* __restrict__ h0,
                         float* __restrict__ s1, float* __restrict__ h1) {
  int i = threadIdx.x;
  if (i < 128) {
    float s = g0[i] * rsqrtf(v0[i] + EPSF);
    s0[i] = s;
    h0[i] = be0[i] + (b0[i] - m0[i]) * s;
  } else {
    int j = i - 128;
    float s = g1[j] * rsqrtf(v1[j] + EPSF);
    s1[j] = s;
    h1[j] = be1[j] + (b1[j] - m1[j]) * s;
  }
}

// ---------------- premul: xs_bf16 = x * dinv[row] ----------------

__global__ __launch_bounds__(256) void premul_k(const float* __restrict__ x,
                                                const float* __restrict__ dinv,
                                                unsigned* __restrict__ xs) {
  int i = blockIdx.x * 256 + threadIdx.x;  // channel-pair index over NN*32
  if (i >= NN * 32) return;
  int n = i >> 5;
  float d = dinv[n];
  float2 v = ((const float2*)x)[i];
  xs[i] = pack_bf16(v.x * d, v.y * d);
}

// ---------------- Aggregation (bf16 in, fp32 accumulate, bf16 out) ----------------
// out[n] = dinv[n] * ( sum_{s} xp[s] + xp[n] ), xp premultiplied by dinv[s].
// One coalesced index load per node (cnt+1 <= 49 <= 64 lanes); self appended as
// pseudo-neighbor. Loops have WAVE-UNIFORM trip counts; __shfl always executes
// with the full wave active (clamped source lane); only the gather/accumulate
// is predicated. (ds_bpermute from an EXEC-inactive lane is undefined — R8 bug.)

// 64-ch: row = 128B = 8 lanes x uint4; 16 edges per iteration (2 in flight).
__global__ __launch_bounds__(256) void aggp64_k(const uint4* __restrict__ xp4,
                                                const int* __restrict__ counts,
                                                const int* __restrict__ csr,
                                                const float* __restrict__ dinv,
                                                uint4* __restrict__ out4) {
  int node = blockIdx.x * 4 + (threadIdx.x >> 6);
  if (node >= NN) return;
  int lane = threadIdx.x & 63;
  int g = lane >> 3, sl = lane & 7;
  int cnt = min(counts[node], CAP);
  int idx = (lane < cnt) ? csr[node * CAP + lane] : node;  // self at pos cnt
  cnt += 1;
  float a[8] = {0.f, 0.f, 0.f, 0.f, 0.f, 0.f, 0.f, 0.f};
  for (int base = 0; base < cnt; base += 16) {   // uniform trip count
    int j0 = base + g, j1 = base + g + 8;
    int s0 = __shfl(idx, min(j0, cnt - 1), 64);  // full wave active
    int s1 = __shfl(idx, min(j1, cnt - 1), 64);
    if (j0 < cnt) acc_u4(a, xp4[(size_t)s0 * 8 + sl]);
    if (j1 < cnt) acc_u4(a, xp4[(size_t)s1 * 8 + sl]);
  }
#pragma unroll
  for (int i = 0; i < 8; ++i) {
    a[i] += __shfl_xor(a[i], 8, 64);
    a[i] += __shfl_xor(a[i], 16, 64);
    a[i] += __shfl_xor(a[i], 32, 64);
  }
  if (g == 0) {
    float di = dinv[node];
    uint4 o;
    o.x = pack_bf16(a[0] * di, a[1] * di);
    o.y = pack_bf16(a[2] * di, a[3] * di);
    o.z = pack_bf16(a[4] * di, a[5] * di);
    o.w = pack_bf16(a[6] * di, a[7] * di);
    out4[(size_t)node * 8 + sl] = o;
  }
}

// 128-ch: row = 256B = 16 lanes x uint4; 16 edges per iteration (4 in flight).
__global__ __launch_bounds__(256) void aggp128_k(const uint4* __restrict__ xp4,
                                                 const int* __restrict__ counts,
                                                 const int* __restrict__ csr,
                                                 const float* __restrict__ dinv,
                                                 uint4* __restrict__ out4) {
  int node = blockIdx.x * 4 + (threadIdx.x >> 6);
  if (node >= NN) return;
  int lane = threadIdx.x & 63;
  int q = lane >> 4, sl = lane & 15;
  int cnt = min(counts[node], CAP);
  int idx = (lane < cnt) ? csr[node * CAP + lane] : node;  // self at pos cnt
  cnt += 1;
  float a[8] = {0.f, 0.f, 0.f, 0.f, 0.f, 0.f, 0.f, 0.f};
  for (int base = 0; base < cnt; base += 16) {   // uniform trip count
    int j0 = base + q, j1 = base + q + 4, j2 = base + q + 8, j3 = base + q + 12;
    int s0 = __shfl(idx, min(j0, cnt - 1), 64);  // full wave active
    int s1 = __shfl(idx, min(j1, cnt - 1), 64);
    int s2 = __shfl(idx, min(j2, cnt - 1), 64);
    int s3 = __shfl(idx, min(j3, cnt - 1), 64);
    if (j0 < cnt) acc_u4(a, xp4[(size_t)s0 * 16 + sl]);
    if (j1 < cnt) acc_u4(a, xp4[(size_t)s1 * 16 + sl]);
    if (j2 < cnt) acc_u4(a, xp4[(size_t)s2 * 16 + sl]);
    if (j3 < cnt) acc_u4(a, xp4[(size_t)s3 * 16 + sl]);
  }
#pragma unroll
  for (int i = 0; i < 8; ++i) {
    a[i] += __shfl_xor(a[i], 16, 64);
    a[i] += __shfl_xor(a[i], 32, 64);
  }
  if (q == 0) {
    float di = dinv[node];
    uint4 o;
    o.x = pack_bf16(a[0] * di, a[1] * di);
    o.y = pack_bf16(a[2] * di, a[3] * di);
    o.z = pack_bf16(a[4] * di, a[5] * di);
    o.w = pack_bf16(a[6] * di, a[7] * di);
    out4[(size_t)node * 16 + sl] = o;
  }
}

// final agg + bias + LayerNorm (64-ch bf16 in, fp32 out), same gather as aggp64.
__global__ __launch_bounds__(256) void agg_ln_k(const uint4* __restrict__ xp4,
                                                const int* __restrict__ counts,
                                                const int* __restrict__ csr,
                                                const float* __restrict__ dinv,
                                                const float* __restrict__ bias,
                                                const float* __restrict__ lng,
                                                const float* __restrict__ lnb,
                                                float* __restrict__ out) {
  int node = blockIdx.x * 4 + (threadIdx.x >> 6);
  if (node >= NN) return;
  int lane = threadIdx.x & 63;
  int g = lane >> 3, sl = lane & 7;
  int cnt = min(counts[node], CAP);
  int idx = (lane < cnt) ? csr[node * CAP + lane] : node;  // self at pos cnt
  cnt += 1;
  float a[8] = {0.f, 0.f, 0.f, 0.f, 0.f, 0.f, 0.f, 0.f};
  for (int base = 0; base < cnt; base += 16) {   // uniform trip count
    int j0 = base + g, j1 = base + g + 8;
    int s0 = __shfl(idx, min(j0, cnt - 1), 64);  // full wave active
    int s1 = __shfl(idx, min(j1, cnt - 1), 64);
    if (j0 < cnt) acc_u4(a, xp4[(size_t)s0 * 8 + sl]);
    if (j1 < cnt) acc_u4(a, xp4[(size_t)s1 * 8 + sl]);
  }
#pragma unroll
  for (int i = 0; i < 8; ++i) {
    a[i] += __shfl_xor(a[i], 8, 64);
    a[i] += __shfl_xor(a[i], 16, 64);
    a[i] += __shfl_xor(a[i], 32, 64);
  }
  // all lanes now hold channels sl*8..sl*8+7
  float di = dinv[node];
  float4 b0 = ((const float4*)bias)[sl * 2];
  float4 b1 = ((const float4*)bias)[sl * 2 + 1];
  float v[8];
  v[0] = a[0] * di + b0.x; v[1] = a[1] * di + b0.y;
  v[2] = a[2] * di + b0.z; v[3] = a[3] * di + b0.w;
  v[4] = a[4] * di + b1.x; v[5] = a[5] * di + b1.y;
  v[6] = a[6] * di + b1.z; v[7] = a[7] * di + b1.w;
  float s = ((v[0] + v[1]) + (v[2] + v[3])) + ((v[4] + v[5]) + (v[6] + v[7]));
#pragma unroll
  for (int off = 1; off < 8; off <<= 1) s += __shfl_xor(s, off, 64);
  float mu = s * (1.f / 64.f);
  float vs = 0.f;
#pragma unroll
  for (int i = 0; i < 8; ++i) {
    v[i] -= mu;
    vs += v[i] * v[i];
  }
#pragma unroll
  for (int off = 1; off < 8; off <<= 1) vs += __shfl_xor(vs, off, 64);
  float r = rsqrtf(vs * (1.f / 64.f) + EPSF);
  if (g == 0) {
    float4 g0 = ((const float4*)lng)[sl * 2];
    float4 g1 = ((const float4*)lng)[sl * 2 + 1];
    float4 e0 = ((const float4*)lnb)[sl * 2];
    float4 e1 = ((const float4*)lnb)[sl * 2 + 1];
    float4 o0, o1;
    o0.x = v[0] * r * g0.x + e0.x; o0.y = v[1] * r * g0.y + e0.y;
    o0.z = v[2] * r * g0.z + e0.z; o0.w = v[3] * r * g0.w + e0.w;
    o1.x = v[4] * r * g1.x + e1.x; o1.y = v[5] * r * g1.y + e1.y;
    o1.z = v[6] * r * g1.z + e1.z; o1.w = v[7] * r * g1.w + e1.w;
    ((float4*)out)[(size_t)node * 16 + sl * 2] = o0;
    ((float4*)out)[(size_t)node * 16 + sl * 2 + 1] = o1;
  }
}

// ---------------- MFMA GEMM: C[N,D] = A[N,K] @ W[K,D], bf16 in/out ----------------

#define EPI_BNRELU 1
#define EPI_BNRELU_PREMUL 2
#define EPI_PREMUL 3

template <int K, int D, int EPI>
__global__ __launch_bounds__(256, 2) void gemm_mfma_k(
    const unsigned short* __restrict__ Abf,   // [N][K] bf16
    const unsigned short* __restrict__ Wt,    // [D][K] bf16 (pre-transposed)
    const float* __restrict__ scale,          // [D]
    const float* __restrict__ shift,          // [D]
    const float* __restrict__ dinv,
    unsigned short* __restrict__ C) {         // [N][D] bf16
  constexpr int BM = 64;
  constexpr int LK = K + 8;                   // +16B pad: 2-way bank alias (free)
  constexpr int NT = D / 16;
  __shared__ unsigned short sA[BM * LK];
  __shared__ unsigned short sW[D * LK];
  int tid = threadIdx.x;
  int row0 = blockIdx.x * BM;
  for (int i = tid; i < BM * K / 8; i += 256) {
    int r = i / (K / 8), c8 = i % (K / 8);
    int gr = row0 + r;
    short8 v = {};
    if (gr < NN) v = *(const short8*)&Abf[(size_t)gr * K + c8 * 8];
    *(short8*)&sA[r * LK + c8 * 8] = v;
  }
  for (int i = tid; i < D * K / 8; i += 256) {
    int d = i / (K / 8), c8 = i % (K / 8);
    *(short8*)&sW[d * LK + c8 * 8] = *(const short8*)&Wt[d * K + c8 * 8];
  }
  __syncthreads();
  int wid = tid >> 6, lane = tid & 63;
  int lr = lane & 15, kg = lane >> 4;
  f32x4 acc[NT];
#pragma unroll
  for (int t = 0; t < NT; ++t) acc[t] = (f32x4){0.f, 0.f, 0.f, 0.f};
  const unsigned short* pa = &sA[(wid * 16 + lr) * LK + kg * 8];
#pragma unroll
  for (int kk = 0; kk < K / 32; ++kk) {
    short8 a = *(const short8*)(pa + kk * 32);
#pragma unroll
    for (int t = 0; t < NT; ++t) {
      short8 b = *(const short8*)&sW[(t * 16 + lr) * LK + kk * 32 + kg * 8];
      acc[t] = __builtin_amdgcn_mfma_f32_16x16x32_bf16(a, b, acc[t], 0, 0, 0);
    }
  }
  int rbase = row0 + wid * 16 + kg * 4;
  float dv[4];
  if (EPI != EPI_BNRELU) {
#pragma unroll
    for (int j = 0; j < 4; ++j) dv[j] = (rbase + j < NN) ? dinv[rbase + j] : 0.f;
  }
#pragma unroll
  for (int t = 0; t < NT; ++t) {
    int col = t * 16 + lr;
    float sc = 1.f, sh = 0.f;
    if (EPI != EPI_PREMUL) { sc = scale[col]; sh = shift[col]; }
#pragma unroll
    for (int j = 0; j < 4; ++j) {
      int r = rbase + j;
      if (r >= NN) continue;
      float v = acc[t][j];
      if (EPI != EPI_PREMUL) v = fmaxf(v * sc + sh, 0.f);
      if (EPI != EPI_BNRELU) v *= dv[j];
      C[(size_t)r * D + col] = bf16_1(v);
    }
  }
}

// ---------------- Pooling (two-stage) ----------------

__global__ void boundaries_k(const int* __restrict__ batch, int* __restrict__ start) {
  int i = blockIdx.x * blockDim.x + threadIdx.x;
  if (i >= NN) return;
  int b = batch[i];
  if (i == 0) {
    for (int g = 0; g <= b; ++g) start[g] = 0;
  } else {
    int p = batch[i - 1];
    for (int g = p + 1; g <= b; ++g) start[g] = i;
  }
  if (i == NN - 1) {
    for (int g = b + 1; g <= GG; ++g) start[g] = NN;
  }
}

__global__ __launch_bounds__(256) void pool1_k(const float* __restrict__ ne,
                                               const int* __restrict__ batch,
                                               float* __restrict__ acc) {
  const int CHUNK = (NN + PB - 1) / PB;  // 98
  int i0 = blockIdx.x * CHUNK;
  int i1 = min(i0 + CHUNK, NN);
  if (i0 >= NN) return;
  int c = threadIdx.x & 63;
  int part = threadIdx.x >> 6;  // 0..3
  int cur = -1;
  float a = 0.f;
  for (int i = i0 + part; i < i1; i += 4) {
    int b = batch[i];  // wave-uniform
    if (b != cur) {
      if (cur >= 0) atomicAdd(&acc[cur * 64 + c], a);
      cur = b;
      a = 0.f;
    }
    a += ne[(size_t)i * 64 + c];
  }
  if (cur >= 0) atomicAdd(&acc[cur * 64 + c], a);
}

__global__ __launch_bounds__(256) void pool2_k(const float* __restrict__ acc,
                                               const int* __restrict__ start,
                                               float* __restrict__ ge) {
  int i = blockIdx.x * 256 + threadIdx.x;
  if (i >= GG * 64) return;
  int g = i >> 6;
  float cnt = (float)(start[g + 1] - start[g]);
  ge[i] = acc[i] / fmaxf(cnt, 1.f);
}

// ---------------- launch ----------------

extern "C" void kernel_launch(void* const* d_in, const int* in_sizes, int n_in,
                              void* d_out, int out_size, void* d_ws, size_t ws_size,
                              hipStream_t stream) {
  const float* x = (const float*)d_in[0];
  const int* ei = (const int*)d_in[1];
  const int* srcv = ei;
  const int* dstv = ei + EE;
  const int* batch = (const int*)d_in[2];
  const float* W0 = (const float*)d_in[3];
  const float* b0 = (const float*)d_in[4];
  const float* W1 = (const float*)d_in[5];
  const float* b1 = (const float*)d_in[6];
  const float* W2 = (const float*)d_in[7];
  const float* b2 = (const float*)d_in[8];
  const float* bn0g = (const float*)d_in[9];
  const float* bn0b = (const float*)d_in[10];
  const float* bn0m = (const float*)d_in[11];
  const float* bn0v = (const float*)d_in[12];
  const float* bn1g = (const float*)d_in[13];
  const float* bn1b = (const float*)d_in[14];
  const float* bn1m = (const float*)d_in[15];
  const float* bn1v = (const float*)d_in[16];
  const float* lng = (const float*)d_in[17];
  const float* lnb = (const float*)d_in[18];

  float* out_nodes = (float*)d_out;
  float* out_graph = out_nodes + (size_t)NN * 64;

  char* ws = (char*)d_ws;
  size_t off = 0;
  auto carve = [&](size_t bytes) {
    void* p = ws + off;
    off = (off + bytes + 255) & ~(size_t)255;
    return p;
  };
  int* cursor = (int*)carve((size_t)NN * 4);          // doubles as counts
  float* dinv = (float*)carve((size_t)NN * 4);
  int* gstart = (int*)carve((size_t)(GG + 1) * 4);
  float* pacc = (float*)carve((size_t)GG * 64 * 4);
  unsigned short* wt0 = (unsigned short*)carve(8192 * 2);    // [128][64]
  unsigned short* wt1 = (unsigned short*)carve(16384 * 2);   // [128][128]
  unsigned short* wt2 = (unsigned short*)carve(8192 * 2);    // [64][128]
  float* s0 = (float*)carve(128 * 4);
  float* h0 = (float*)carve(128 * 4);
  float* s1 = (float*)carve(128 * 4);
  float* h1 = (float*)carve(128 * 4);
  int* csr = (int*)carve((size_t)NN * CAP * 4);       // 19.2 MB
  void* bufA = carve((size_t)NN * 128 * 4);
  void* bufB = carve((size_t)NN * 128 * 4);

  hipMemsetAsync(cursor, 0, (size_t)NN * 4, stream);
  hipMemsetAsync(pacc, 0, (size_t)GG * 64 * 4, stream);

  int eg = (EE + 255) / 256;  // 6250
  int ng = NB;                // 391

  wprep_k<<<128, 256, 0, stream>>>(W0, W1, W2, wt0, wt1, wt2);
  bnprep_k<<<1, 256, 0, stream>>>(b0, bn0g, bn0b, bn0m, bn0v,
                                  b1, bn1g, bn1b, bn1m, bn1v, s0, h0, s1, h1);
  for (int p = 0; p < 4; ++p) {
    int lo = p * (NN / 4), hi = (p == 3) ? NN : (p + 1) * (NN / 4);
    fill_mp<<<eg, 256, 0, stream>>>(srcv, dstv, lo, hi, cursor, csr);
  }
  prep_k<<<ng, 256, 0, stream>>>(cursor, dinv);
  boundaries_k<<<ng, 256, 0, stream>>>(batch, gstart);

  int agrid = (NN + 3) / 4;    // 25000
  int mgrid = (NN + 63) / 64;  // 1563

  // xs_bf16 = x * dinv -> bufA
  premul_k<<<(NN * 32 + 255) / 256, 256, 0, stream>>>(x, dinv, (unsigned*)bufA);
  // a0 = agg(xs) -> bufB (bf16, 64ch)
  aggp64_k<<<agrid, 256, 0, stream>>>((const uint4*)bufA, cursor, csr, dinv,
                                      (uint4*)bufB);
  // h0p = relu(bn(a0@W0)) * dinv -> bufA (bf16, 128ch)
  gemm_mfma_k<64, 128, EPI_BNRELU_PREMUL><<<mgrid, 256, 0, stream>>>(
      (const unsigned short*)bufB, wt0, s0, h0, dinv, (unsigned short*)bufA);
  // a1 = agg(h0p) -> bufB (bf16, 128ch)
  aggp128_k<<<agrid, 256, 0, stream>>>((const uint4*)bufA, cursor, csr, dinv,
                                       (uint4*)bufB);
  // h1 = relu(bn(a1@W1)) -> bufA (bf16, 128ch)
  gemm_mfma_k<128, 128, EPI_BNRELU><<<mgrid, 256, 0, stream>>>(
      (const unsigned short*)bufB, wt1, s1, h1, dinv, (unsigned short*)bufA);
  // xw2p = (h1@W2) * dinv -> bufB (bf16, 64ch; bias b2 post-agg)
  gemm_mfma_k<128, 64, EPI_PREMUL><<<mgrid, 256, 0, stream>>>(
      (const unsigned short*)bufA, wt2, s1, h1, dinv, (unsigned short*)bufB);
  // out_nodes = LN(agg(xw2p) + b2)
  agg_ln_k<<<agrid, 256, 0, stream>>>((const uint4*)bufB, cursor, csr, dinv, b2,
                                      lng, lnb, out_nodes);
  // two-stage graph mean pool
  pool1_k<<<PB, 256, 0, stream>>>(out_nodes, batch, pacc);
  pool2_k<<<(GG * 64 + 255) / 256, 256, 0, stream>>>(pacc, gstart, out_graph);
}

// Round 10
// 342.841 us; speedup vs baseline: 4.0672x; 1.0396x over previous
//
#include <hip/hip_runtime.h>

#define NN 100000
#define EE 1600000
#define GG 64
#define EPSF 1e-5f
#define NB 391   // ceil(NN/256)
#define CAP 48   // CSR slots per node (Poisson(16); P(any overflow) ~ 6e-6)
#define PB 1024  // pool stage-1 blocks

typedef short short8 __attribute__((ext_vector_type(8)));
typedef float f32x4 __attribute__((ext_vector_type(4)));

// ---------------- bf16 helpers ----------------

__device__ __forceinline__ unsigned pack_bf16(float a, float b) {
  unsigned ua = __float_as_uint(a);
  unsigned ub = __float_as_uint(b);
  ua = (ua + 0x7fffu + ((ua >> 16) & 1u)) >> 16;           // RNE, low half
  ub = (ub + 0x7fffu + ((ub >> 16) & 1u)) & 0xffff0000u;   // RNE, high half
  return ua | ub;
}
__device__ __forceinline__ unsigned short bf16_1(float a) {
  unsigned u = __float_as_uint(a);
  return (unsigned short)((u + 0x7fffu + ((u >> 16) & 1u)) >> 16);
}
__device__ __forceinline__ float blo(unsigned u) { return __uint_as_float(u << 16); }
__device__ __forceinline__ float bhi(unsigned u) { return __uint_as_float(u & 0xffff0000u); }

__device__ __forceinline__ void acc_u4(float* a, uint4 u) {
  a[0] += blo(u.x); a[1] += bhi(u.x);
  a[2] += blo(u.y); a[3] += bhi(u.y);
  a[4] += blo(u.z); a[5] += bhi(u.z);
  a[6] += blo(u.w); a[7] += bhi(u.w);
}

// 32-bit voffset gather (SADDR + unsigned byte offset)
__device__ __forceinline__ uint4 ldg_off(const void* base, unsigned off) {
  return *(const uint4*)((const char*)base + off);
}

// ---------------- CSR build: fixed-cap slots, range-filtered passes ----------------

__global__ void fill_mp(const int* __restrict__ src, const int* __restrict__ dst,
                        int lo, int hi, int* __restrict__ cursor,
                        int* __restrict__ csr) {
  int e = blockIdx.x * 256 + threadIdx.x;
  if (e >= EE) return;
  int d = dst[e];
  if (d < lo || d >= hi) return;
  int pos = atomicAdd(&cursor[d], 1);
  if (pos < CAP) csr[d * CAP + pos] = src[e];
}

// ---------------- merged setup: weight transpose+bf16, BN fold, graph bounds ----

__global__ __launch_bounds__(256) void setup_k(
    const float* __restrict__ W0, const float* __restrict__ W1,
    const float* __restrict__ W2, unsigned short* __restrict__ wt0,
    unsigned short* __restrict__ wt1, unsigned short* __restrict__ wt2,
    const float* __restrict__ b0, const float* __restrict__ g0,
    const float* __restrict__ be0, const float* __restrict__ m0,
    const float* __restrict__ v0, const float* __restrict__ b1,
    const float* __restrict__ g1, const float* __restrict__ be1,
    const float* __restrict__ m1, const float* __restrict__ v1,
    float* __restrict__ s0, float* __restrict__ h0,
    float* __restrict__ s1, float* __restrict__ h1,
    const int* __restrict__ batch, int* __restrict__ start) {
  int bid = blockIdx.x;
  if (bid < 128) {                       // weight prep
    int i = bid * 256 + threadIdx.x;
    if (i < 8192) {                      // Wt0 [128][64]
      int d = i >> 6, k = i & 63;
      wt0[d * 64 + k] = bf16_1(W0[k * 128 + d]);
    } else if (i < 24576) {              // Wt1 [128][128]
      int j = i - 8192;
      int d = j >> 7, k = j & 127;
      wt1[d * 128 + k] = bf16_1(W1[k * 128 + d]);
    } else if (i < 32768) {              // Wt2 [64][128]
      int j = i - 24576;
      int d = j >> 7, k = j & 127;
      wt2[d * 128 + k] = bf16_1(W2[k * 64 + d]);
    }
  } else if (bid == 128) {               // BN fold
    int i = threadIdx.x;
    if (i < 128) {
      float s = g0[i] * rsqrtf(v0[i] + EPSF);
      s0[i] = s;
      h0[i] = be0[i] + (b0[i] - m0[i]) * s;
    } else {
      int j = i - 128;
      float s = g1[j] * rsqrtf(v1[j] + EPSF);
      s1[j] = s;
      h1[j] = be1[j] + (b1[j] - m1[j]) * s;
    }
  } else {                               // graph boundaries
    int i = (bid - 129) * 256 + threadIdx.x;
    if (i >= NN) return;
    int b = batch[i];
    if (i == 0) {
      for (int g = 0; g <= b; ++g) start[g] = 0;
    } else {
      int p = batch[i - 1];
      for (int g = p + 1; g <= b; ++g) start[g] = i;
    }
    if (i == NN - 1) {
      for (int g = b + 1; g <= GG; ++g) start[g] = NN;
    }
  }
}

// ---------------- premul: xs_bf16 = x * rsqrt(deg) ----------------

__global__ __launch_bounds__(256) void premul_k(const float* __restrict__ x,
                                                const int* __restrict__ counts,
                                                unsigned* __restrict__ xs) {
  int i = blockIdx.x * 256 + threadIdx.x;  // channel-pair index over NN*32
  if (i >= NN * 32) return;
  int n = i >> 5;
  float d = rsqrtf((float)counts[n] + 1.0f);
  float2 v = ((const float2*)x)[i];
  xs[i] = pack_bf16(v.x * d, v.y * d);
}

// ---------------- Aggregation (bf16 in, fp32 accumulate, bf16 out) ----------------
// out[n] = dinv[n] * ( sum_{s} xp[s] + xp[n] ), xp premultiplied by dinv[s].
// One coalesced index load per node; self appended as pseudo-neighbor.
// Loops have WAVE-UNIFORM trip counts; __shfl always full-wave (lane < 64 by
// construction: base < cnt <= 49, group offset <= 15). Only gathers predicated.

// 64-ch: row = 128B = 8 lanes x uint4; 16 edges per iteration (2 in flight).
__global__ __launch_bounds__(256) void aggp64_k(const unsigned* __restrict__ xp,
                                                const int* __restrict__ counts,
                                                const int* __restrict__ csr,
                                                uint4* __restrict__ out4) {
  int node = blockIdx.x * 4 + (threadIdx.x >> 6);
  if (node >= NN) return;
  int lane = threadIdx.x & 63;
  int g = lane >> 3, sl = lane & 7;
  int raw = counts[node];
  float di = rsqrtf((float)raw + 1.0f);
  int cnt = min(raw, CAP);
  int idx = (lane < cnt) ? csr[node * CAP + lane] : node;  // self at pos cnt
  cnt += 1;
  unsigned slb = (unsigned)(sl << 4);
  float a[8] = {0.f, 0.f, 0.f, 0.f, 0.f, 0.f, 0.f, 0.f};
  for (int base = 0; base < cnt; base += 16) {   // uniform trip count
    int j0 = base + g, j1 = base + g + 8;
    int s0 = __shfl(idx, j0, 64);                // j <= 63 always
    int s1 = __shfl(idx, j1, 64);
    if (j0 < cnt) acc_u4(a, ldg_off(xp, (unsigned)s0 * 128u + slb));
    if (j1 < cnt) acc_u4(a, ldg_off(xp, (unsigned)s1 * 128u + slb));
  }
#pragma unroll
  for (int i = 0; i < 8; ++i) {
    a[i] += __shfl_xor(a[i], 8, 64);
    a[i] += __shfl_xor(a[i], 16, 64);
    a[i] += __shfl_xor(a[i], 32, 64);
  }
  if (g == 0) {
    uint4 o;
    o.x = pack_bf16(a[0] * di, a[1] * di);
    o.y = pack_bf16(a[2] * di, a[3] * di);
    o.z = pack_bf16(a[4] * di, a[5] * di);
    o.w = pack_bf16(a[6] * di, a[7] * di);
    out4[(size_t)node * 8 + sl] = o;
  }
}

// 128-ch: row = 256B = 16 lanes x uint4; 16 edges per iteration (4 in flight).
__global__ __launch_bounds__(256) void aggp128_k(const unsigned* __restrict__ xp,
                                                 const int* __restrict__ counts,
                                                 const int* __restrict__ csr,
                                                 uint4* __restrict__ out4) {
  int node = blockIdx.x * 4 + (threadIdx.x >> 6);
  if (node >= NN) return;
  int lane = threadIdx.x & 63;
  int q = lane >> 4, sl = lane & 15;
  int raw = counts[node];
  float di = rsqrtf((float)raw + 1.0f);
  int cnt = min(raw, CAP);
  int idx = (lane < cnt) ? csr[node * CAP + lane] : node;  // self at pos cnt
  cnt += 1;
  unsigned slb = (unsigned)(sl << 4);
  float a[8] = {0.f, 0.f, 0.f, 0.f, 0.f, 0.f, 0.f, 0.f};
  for (int base = 0; base < cnt; base += 16) {   // uniform trip count
    int j0 = base + q, j1 = base + q + 4, j2 = base + q + 8, j3 = base + q + 12;
    int s0 = __shfl(idx, j0, 64);                // j <= 63 always
    int s1 = __shfl(idx, j1, 64);
    int s2 = __shfl(idx, j2, 64);
    int s3 = __shfl(idx, j3, 64);
    if (j0 < cnt) acc_u4(a, ldg_off(xp, (unsigned)s0 * 256u + slb));
    if (j1 < cnt) acc_u4(a, ldg_off(xp, (unsigned)s1 * 256u + slb));
    if (j2 < cnt) acc_u4(a, ldg_off(xp, (unsigned)s2 * 256u + slb));
    if (j3 < cnt) acc_u4(a, ldg_off(xp, (unsigned)s3 * 256u + slb));
  }
#pragma unroll
  for (int i = 0; i < 8; ++i) {
    a[i] += __shfl_xor(a[i], 16, 64);
    a[i] += __shfl_xor(a[i], 32, 64);
  }
  if (q == 0) {
    uint4 o;
    o.x = pack_bf16(a[0] * di, a[1] * di);
    o.y = pack_bf16(a[2] * di, a[3] * di);
    o.z = pack_bf16(a[4] * di, a[5] * di);
    o.w = pack_bf16(a[6] * di, a[7] * di);
    out4[(size_t)node * 16 + sl] = o;
  }
}

// final agg + bias + LayerNorm (64-ch bf16 in, fp32 out), eighth-wave gather.
__global__ __launch_bounds__(256) void agg_ln_k(const unsigned* __restrict__ xp,
                                                const int* __restrict__ counts,
                                                const int* __restrict__ csr,
                                                const float* __restrict__ bias,
                                                const float* __restrict__ lng,
                                                const float* __restrict__ lnb,
                                                float* __restrict__ out) {
  int node = blockIdx.x * 4 + (threadIdx.x >> 6);
  if (node >= NN) return;
  int lane = threadIdx.x & 63;
  int g = lane >> 3, sl = lane & 7;
  int raw = counts[node];
  float di = rsqrtf((float)raw + 1.0f);
  int cnt = min(raw, CAP);
  int idx = (lane < cnt) ? csr[node * CAP + lane] : node;  // self at pos cnt
  cnt += 1;
  unsigned slb = (unsigned)(sl << 4);
  float a[8] = {0.f, 0.f, 0.f, 0.f, 0.f, 0.f, 0.f, 0.f};
  for (int base = 0; base < cnt; base += 16) {   // uniform trip count
    int j0 = base + g, j1 = base + g + 8;
    int s0 = __shfl(idx, j0, 64);                // j <= 63 always
    int s1 = __shfl(idx, j1, 64);
    if (j0 < cnt) acc_u4(a, ldg_off(xp, (unsigned)s0 * 128u + slb));
    if (j1 < cnt) acc_u4(a, ldg_off(xp, (unsigned)s1 * 128u + slb));
  }
#pragma unroll
  for (int i = 0; i < 8; ++i) {
    a[i] += __shfl_xor(a[i], 8, 64);
    a[i] += __shfl_xor(a[i], 16, 64);
    a[i] += __shfl_xor(a[i], 32, 64);
  }
  // all lanes now hold channels sl*8..sl*8+7
  float4 b0 = ((const float4*)bias)[sl * 2];
  float4 b1 = ((const float4*)bias)[sl * 2 + 1];
  float v[8];
  v[0] = a[0] * di + b0.x; v[1] = a[1] * di + b0.y;
  v[2] = a[2] * di + b0.z; v[3] = a[3] * di + b0.w;
  v[4] = a[4] * di + b1.x; v[5] = a[5] * di + b1.y;
  v[6] = a[6] * di + b1.z; v[7] = a[7] * di + b1.w;
  float s = ((v[0] + v[1]) + (v[2] + v[3])) + ((v[4] + v[5]) + (v[6] + v[7]));
#pragma unroll
  for (int off = 1; off < 8; off <<= 1) s += __shfl_xor(s, off, 64);
  float mu = s * (1.f / 64.f);
  float vs = 0.f;
#pragma unroll
  for (int i = 0; i < 8; ++i) {
    v[i] -= mu;
    vs += v[i] * v[i];
  }
#pragma unroll
  for (int off = 1; off < 8; off <<= 1) vs += __shfl_xor(vs, off, 64);
  float r = rsqrtf(vs * (1.f / 64.f) + EPSF);
  if (g == 0) {
    float4 g0 = ((const float4*)lng)[sl * 2];
    float4 g1 = ((const float4*)lng)[sl * 2 + 1];
    float4 e0 = ((const float4*)lnb)[sl * 2];
    float4 e1 = ((const float4*)lnb)[sl * 2 + 1];
    float4 o0, o1;
    o0.x = v[0] * r * g0.x + e0.x; o0.y = v[1] * r * g0.y + e0.y;
    o0.z = v[2] * r * g0.z + e0.z; o0.w = v[3] * r * g0.w + e0.w;
    o1.x = v[4] * r * g1.x + e1.x; o1.y = v[5] * r * g1.y + e1.y;
    o1.z = v[6] * r * g1.z + e1.z; o1.w = v[7] * r * g1.w + e1.w;
    ((float4*)out)[(size_t)node * 16 + sl * 2] = o0;
    ((float4*)out)[(size_t)node * 16 + sl * 2 + 1] = o1;
  }
}

// ---------------- MFMA GEMM: C[N,D] = A[N,K] @ W[K,D], bf16 in/out ----------------

#define EPI_BNRELU 1
#define EPI_BNRELU_PREMUL 2
#define EPI_PREMUL 3

template <int K, int D, int EPI>
__global__ __launch_bounds__(256, 2) void gemm_mfma_k(
    const unsigned short* __restrict__ Abf,   // [N][K] bf16
    const unsigned short* __restrict__ Wt,    // [D][K] bf16 (pre-transposed)
    const float* __restrict__ scale,          // [D]
    const float* __restrict__ shift,          // [D]
    const int* __restrict__ counts,
    unsigned short* __restrict__ C) {         // [N][D] bf16
  constexpr int BM = 64;
  constexpr int LK = K + 8;                   // +16B pad: 2-way bank alias (free)
  constexpr int NT = D / 16;
  __shared__ unsigned short sA[BM * LK];
  __shared__ unsigned short sW[D * LK];
  int tid = threadIdx.x;
  int row0 = blockIdx.x * BM;
  for (int i = tid; i < BM * K / 8; i += 256) {
    int r = i / (K / 8), c8 = i % (K / 8);
    int gr = row0 + r;
    short8 v = {};
    if (gr < NN) v = *(const short8*)&Abf[(size_t)gr * K + c8 * 8];
    *(short8*)&sA[r * LK + c8 * 8] = v;
  }
  for (int i = tid; i < D * K / 8; i += 256) {
    int d = i / (K / 8), c8 = i % (K / 8);
    *(short8*)&sW[d * LK + c8 * 8] = *(const short8*)&Wt[d * K + c8 * 8];
  }
  __syncthreads();
  int wid = tid >> 6, lane = tid & 63;
  int lr = lane & 15, kg = lane >> 4;
  f32x4 acc[NT];
#pragma unroll
  for (int t = 0; t < NT; ++t) acc[t] = (f32x4){0.f, 0.f, 0.f, 0.f};
  const unsigned short* pa = &sA[(wid * 16 + lr) * LK + kg * 8];
#pragma unroll
  for (int kk = 0; kk < K / 32; ++kk) {
    short8 a = *(const short8*)(pa + kk * 32);
#pragma unroll
    for (int t = 0; t < NT; ++t) {
      short8 b = *(const short8*)&sW[(t * 16 + lr) * LK + kk * 32 + kg * 8];
      acc[t] = __builtin_amdgcn_mfma_f32_16x16x32_bf16(a, b, acc[t], 0, 0, 0);
    }
  }
  int rbase = row0 + wid * 16 + kg * 4;
  float dv[4];
  if (EPI != EPI_BNRELU) {
#pragma unroll
    for (int j = 0; j < 4; ++j)
      dv[j] = (rbase + j < NN) ? rsqrtf((float)counts[rbase + j] + 1.0f) : 0.f;
  }
#pragma unroll
  for (int t = 0; t < NT; ++t) {
    int col = t * 16 + lr;
    float sc = 1.f, sh = 0.f;
    if (EPI != EPI_PREMUL) { sc = scale[col]; sh = shift[col]; }
#pragma unroll
    for (int j = 0; j < 4; ++j) {
      int r = rbase + j;
      if (r >= NN) continue;
      float v = acc[t][j];
      if (EPI != EPI_PREMUL) v = fmaxf(v * sc + sh, 0.f);
      if (EPI != EPI_BNRELU) v *= dv[j];
      C[(size_t)r * D + col] = bf16_1(v);
    }
  }
}

// ---------------- Pooling (two-stage) ----------------

__global__ __launch_bounds__(256) void pool1_k(const float* __restrict__ ne,
                                               const int* __restrict__ batch,
                                               float* __restrict__ acc) {
  const int CHUNK = (NN + PB - 1) / PB;  // 98
  int i0 = blockIdx.x * CHUNK;
  int i1 = min(i0 + CHUNK, NN);
  if (i0 >= NN) return;
  int c = threadIdx.x & 63;
  int part = threadIdx.x >> 6;  // 0..3
  int cur = -1;
  float a = 0.f;
  for (int i = i0 + part; i < i1; i += 4) {
    int b = batch[i];  // wave-uniform
    if (b != cur) {
      if (cur >= 0) atomicAdd(&acc[cur * 64 + c], a);
      cur = b;
      a = 0.f;
    }
    a += ne[(size_t)i * 64 + c];
  }
  if (cur >= 0) atomicAdd(&acc[cur * 64 + c], a);
}

__global__ __launch_bounds__(256) void pool2_k(const float* __restrict__ acc,
                                               const int* __restrict__ start,
                                               float* __restrict__ ge) {
  int i = blockIdx.x * 256 + threadIdx.x;
  if (i >= GG * 64) return;
  int g = i >> 6;
  float cnt = (float)(start[g + 1] - start[g]);
  ge[i] = acc[i] / fmaxf(cnt, 1.f);
}

// ---------------- launch ----------------

extern "C" void kernel_launch(void* const* d_in, const int* in_sizes, int n_in,
                              void* d_out, int out_size, void* d_ws, size_t ws_size,
                              hipStream_t stream) {
  const float* x = (const float*)d_in[0];
  const int* ei = (const int*)d_in[1];
  const int* srcv = ei;
  const int* dstv = ei + EE;
  const int* batch = (const int*)d_in[2];
  const float* W0 = (const float*)d_in[3];
  const float* b0 = (const float*)d_in[4];
  const float* W1 = (const float*)d_in[5];
  const float* b1 = (const float*)d_in[6];
  const float* W2 = (const float*)d_in[7];
  const float* b2 = (const float*)d_in[8];
  const float* bn0g = (const float*)d_in[9];
  const float* bn0b = (const float*)d_in[10];
  const float* bn0m = (const float*)d_in[11];
  const float* bn0v = (const float*)d_in[12];
  const float* bn1g = (const float*)d_in[13];
  const float* bn1b = (const float*)d_in[14];
  const float* bn1m = (const float*)d_in[15];
  const float* bn1v = (const float*)d_in[16];
  const float* lng = (const float*)d_in[17];
  const float* lnb = (const float*)d_in[18];

  float* out_nodes = (float*)d_out;
  float* out_graph = out_nodes + (size_t)NN * 64;

  char* ws = (char*)d_ws;
  size_t off = 0;
  auto carve = [&](size_t bytes) {
    void* p = ws + off;
    off = (off + bytes + 255) & ~(size_t)255;
    return p;
  };
  int* cursor = (int*)carve((size_t)NN * 4);          // counts (unclamped)
  float* pacc = (float*)carve((size_t)GG * 64 * 4);   // adjacent: single memset
  int* gstart = (int*)carve((size_t)(GG + 1) * 4);
  unsigned short* wt0 = (unsigned short*)carve(8192 * 2);    // [128][64]
  unsigned short* wt1 = (unsigned short*)carve(16384 * 2);   // [128][128]
  unsigned short* wt2 = (unsigned short*)carve(8192 * 2);    // [64][128]
  float* s0 = (float*)carve(128 * 4);
  float* h0 = (float*)carve(128 * 4);
  float* s1 = (float*)carve(128 * 4);
  float* h1 = (float*)carve(128 * 4);
  int* csr = (int*)carve((size_t)NN * CAP * 4);       // 19.2 MB
  void* bufA = carve((size_t)NN * 128 * 4);
  void* bufB = carve((size_t)NN * 128 * 4);

  // one memset spans cursor (400000B, padded to 400128) + pacc (16384B)
  hipMemsetAsync(cursor, 0, 400128 + 16384, stream);

  int eg = (EE + 255) / 256;  // 6250

  setup_k<<<129 + NB, 256, 0, stream>>>(W0, W1, W2, wt0, wt1, wt2,
                                        b0, bn0g, bn0b, bn0m, bn0v,
                                        b1, bn1g, bn1b, bn1m, bn1v,
                                        s0, h0, s1, h1, batch, gstart);
  for (int p = 0; p < 4; ++p) {
    int lo = p * (NN / 4), hi = (p == 3) ? NN : (p + 1) * (NN / 4);
    fill_mp<<<eg, 256, 0, stream>>>(srcv, dstv, lo, hi, cursor, csr);
  }

  int agrid = (NN + 3) / 4;    // 25000
  int mgrid = (NN + 63) / 64;  // 1563

  // xs_bf16 = x * dinv -> bufA
  premul_k<<<(NN * 32 + 255) / 256, 256, 0, stream>>>(x, cursor, (unsigned*)bufA);
  // a0 = agg(xs) -> bufB (bf16, 64ch)
  aggp64_k<<<agrid, 256, 0, stream>>>((const unsigned*)bufA, cursor, csr,
                                      (uint4*)bufB);
  // h0p = relu(bn(a0@W0)) * dinv -> bufA (bf16, 128ch)
  gemm_mfma_k<64, 128, EPI_BNRELU_PREMUL><<<mgrid, 256, 0, stream>>>(
      (const unsigned short*)bufB, wt0, s0, h0, cursor, (unsigned short*)bufA);
  // a1 = agg(h0p) -> bufB (bf16, 128ch)
  aggp128_k<<<agrid, 256, 0, stream>>>((const unsigned*)bufA, cursor, csr,
                                       (uint4*)bufB);
  // h1 = relu(bn(a1@W1)) -> bufA (bf16, 128ch)
  gemm_mfma_k<128, 128, EPI_BNRELU><<<mgrid, 256, 0, stream>>>(
      (const unsigned short*)bufB, wt1, s1, h1, cursor, (unsigned short*)bufA);
  // xw2p = (h1@W2) * dinv -> bufB (bf16, 64ch; bias b2 post-agg)
  gemm_mfma_k<128, 64, EPI_PREMUL><<<mgrid, 256, 0, stream>>>(
      (const unsigned short*)bufA, wt2, s1, h1, cursor, (unsigned short*)bufB);
  // out_nodes = LN(agg(xw2p) + b2)
  agg_ln_k<<<agrid, 256, 0, stream>>>((const unsigned*)bufB, cursor, csr, b2,
                                      lng, lnb, out_nodes);
  // two-stage graph mean pool
  pool1_k<<<PB, 256, 0, stream>>>(out_nodes, batch, pacc);
  pool2_k<<<(GG * 64 + 255) / 256, 256, 0, stream>>>(pacc, gstart, out_graph);
}